// Round 5
// baseline (401.372 us; speedup 1.0000x reference)
//
#include <hip/hip_runtime.h>

#define NBATCH 16
#define NPTS   2048
#define MQ     2025
#define CWDIM  512
#define NROWS  32400

typedef __attribute__((ext_vector_type(8))) short bf16x8;
typedef __attribute__((ext_vector_type(4))) float f32x4;
typedef unsigned int as1_u32 __attribute__((address_space(1)));
typedef unsigned int as3_u32 __attribute__((address_space(3)));

// ---------- helpers ----------
__device__ __forceinline__ unsigned fkey(float f) {
  unsigned u = __float_as_uint(f);
  return (u & 0x80000000u) ? ~u : (u | 0x80000000u);
}
__device__ __forceinline__ float funkey(unsigned u) {
  unsigned v = (u & 0x80000000u) ? (u ^ 0x80000000u) : ~u;
  return __uint_as_float(v);
}
__device__ __forceinline__ unsigned short f2bf(float f) {  // RNE f32->bf16
  unsigned u = __float_as_uint(f);
  u = (u + 0x7FFFu + ((u >> 16) & 1u)) >> 16;
  return (unsigned short)u;
}
__device__ __forceinline__ void gload_lds16(const void* g, void* l) {
  __builtin_amdgcn_global_load_lds((const as1_u32*)g, (as3_u32*)l, 16, 0, 0);
}

// =====================================================================
// Generic 32x32 transpose + f32->bf16 convert.
// =====================================================================
__global__ __launch_bounds__(256) void tconv_kernel(
    const float* __restrict__ f1w2, const float* __restrict__ f2w2,
    const float* __restrict__ ew2,  const float* __restrict__ ew3,
    unsigned short* __restrict__ w2T, unsigned short* __restrict__ ew2T,
    unsigned short* __restrict__ ew3T)
{
  __shared__ float tile[32][33];
  const int blk = blockIdx.x;
  const float* src; unsigned short* dst; int K, N, tidx;
  if (blk < 256)      { src = f1w2; dst = w2T;            K = 512; N = 512; tidx = blk; }
  else if (blk < 512) { src = f2w2; dst = w2T + 262144;   K = 512; N = 512; tidx = blk - 256; }
  else if (blk < 520) { src = ew2;  dst = ew2T;           K = 64;  N = 128; tidx = blk - 512; }
  else                { src = ew3;  dst = ew3T;           K = 128; N = 512; tidx = blk - 520; }
  const int ntn = N >> 5;
  const int kt = tidx / ntn, nt = tidx - kt * ntn;
  const int tx = threadIdx.x & 31, ty = threadIdx.x >> 5;
  #pragma unroll
  for (int j = 0; j < 4; ++j)
    tile[ty + 8 * j][tx] = src[(size_t)(kt * 32 + ty + 8 * j) * N + nt * 32 + tx];
  __syncthreads();
  #pragma unroll
  for (int j = 0; j < 4; ++j)
    dst[(size_t)(nt * 32 + ty + 8 * j) * K + kt * 32 + tx] = f2bf(tile[tx][ty + 8 * j]);
}

// =====================================================================
// Encoder (MFMA): block = 64 points, 512 thr = 8 waves.
// launch_bounds (512,2): (512,4) capped VGPRs at 64 -> spill (R3/R4 counters)
// =====================================================================
__global__ __launch_bounds__(512, 2) void enc2_kernel(
    const float* __restrict__ pts,
    const float* __restrict__ ew1, const float* __restrict__ eb1,
    const unsigned short* __restrict__ ew2T, const float* __restrict__ eb2,
    const unsigned short* __restrict__ ew3T, const float* __restrict__ eb3,
    unsigned* __restrict__ keys)
{
  __shared__ unsigned short h1s[64 * 64];
  __shared__ unsigned short h2s[64 * 128];
  __shared__ float s_pts[64][4];
  const int t = threadIdx.x;
  const int b = blockIdx.x >> 5, p0 = (blockIdx.x & 31) << 6;
  if (t < 64)
    *(float4*)&s_pts[t][0] = *(const float4*)(pts + ((size_t)b * NPTS + p0 + t) * 4);
  __syncthreads();

  {
    const int c = t & 63;
    const float w0 = ew1[c], w1 = ew1[64 + c], w2 = ew1[128 + c], w3 = ew1[192 + c];
    const float bb = eb1[c];
    #pragma unroll
    for (int i = 0; i < 8; ++i) {
      const int p = i * 8 + (t >> 6);
      float acc = bb + s_pts[p][0] * w0 + s_pts[p][1] * w1 + s_pts[p][2] * w2 + s_pts[p][3] * w3;
      unsigned byte = ((unsigned)p << 7) + ((unsigned)c << 1);
      byte ^= ((unsigned)(p & 7)) << 4;
      h1s[byte >> 1] = f2bf(fmaxf(acc, 0.f));
    }
  }
  __syncthreads();

  const int wv = t >> 6, lane = t & 63, l15 = lane & 15, hi = lane >> 4;

  {
    f32x4 acc[4];
    #pragma unroll
    for (int m = 0; m < 4; ++m) acc[m] = (f32x4){0.f, 0.f, 0.f, 0.f};
    const int col = 16 * wv + l15;
    #pragma unroll
    for (int kk = 0; kk < 64; kk += 32) {
      bf16x8 bv = *(const bf16x8*)(ew2T + (size_t)col * 64 + kk + hi * 8);
      #pragma unroll
      for (int m = 0; m < 4; ++m) {
        const int row = 16 * m + l15;
        unsigned byte = ((unsigned)row << 7) + ((unsigned)((kk + hi * 8)) << 1);
        byte ^= ((unsigned)(row & 7)) << 4;
        bf16x8 av = *(const bf16x8*)&h1s[byte >> 1];
        acc[m] = __builtin_amdgcn_mfma_f32_16x16x32_bf16(av, bv, acc[m], 0, 0, 0);
      }
    }
    const float b2c = eb2[col];
    #pragma unroll
    for (int m = 0; m < 4; ++m)
      #pragma unroll
      for (int r = 0; r < 4; ++r) {
        const int row = 16 * m + hi * 4 + r;
        unsigned byte = ((unsigned)row << 8) + ((unsigned)col << 1);
        byte ^= ((unsigned)(row & 7)) << 4;
        h2s[byte >> 1] = f2bf(fmaxf(acc[m][r] + b2c, 0.f));
      }
  }
  __syncthreads();

  {
    f32x4 acc[4][4];
    #pragma unroll
    for (int m = 0; m < 4; ++m)
      #pragma unroll
      for (int n = 0; n < 4; ++n) acc[m][n] = (f32x4){0.f, 0.f, 0.f, 0.f};
    #pragma unroll
    for (int kk = 0; kk < 128; kk += 32) {
      bf16x8 av[4];
      #pragma unroll
      for (int m = 0; m < 4; ++m) {
        const int row = 16 * m + l15;
        unsigned byte = ((unsigned)row << 8) + ((unsigned)(kk + hi * 8) << 1);
        byte ^= ((unsigned)(row & 7)) << 4;
        av[m] = *(const bf16x8*)&h2s[byte >> 1];
      }
      #pragma unroll
      for (int n = 0; n < 4; ++n) {
        const int col = 64 * wv + 16 * n + l15;
        bf16x8 bv = *(const bf16x8*)(ew3T + (size_t)col * 128 + kk + hi * 8);
        #pragma unroll
        for (int m = 0; m < 4; ++m)
          acc[m][n] = __builtin_amdgcn_mfma_f32_16x16x32_bf16(av[m], bv, acc[m][n], 0, 0, 0);
      }
    }
    #pragma unroll
    for (int n = 0; n < 4; ++n) {
      const int col = 64 * wv + 16 * n + l15;
      float mx = -1e30f;
      #pragma unroll
      for (int m = 0; m < 4; ++m)
        #pragma unroll
        for (int r = 0; r < 4; ++r) mx = fmaxf(mx, acc[m][n][r]);
      mx = fmaxf(mx, __shfl_xor(mx, 16));
      mx = fmaxf(mx, __shfl_xor(mx, 32));
      if (hi == 0) atomicMax(&keys[b * CWDIM + col], fkey(mx + eb3[col]));
    }
  }
}

__global__ __launch_bounds__(256) void decode_kernel(const unsigned* __restrict__ keys,
                                                     float* __restrict__ theta) {
  int i = blockIdx.x * 256 + threadIdx.x;
  theta[i] = funkey(keys[i]);
}

// =====================================================================
// h1base split-K x2: atomicAdd partials (h1b pre-zeroed by memset)
// =====================================================================
__global__ __launch_bounds__(256) void h1base_kernel(
    const float* __restrict__ theta,
    const float* __restrict__ f1w1, const float* __restrict__ f1b1,
    const float* __restrict__ f2w1, const float* __restrict__ f2b1,
    float* __restrict__ h1b)
{
  int gid = blockIdx.x * 256 + threadIdx.x;   // 32768
  int half = gid >> 14;
  int rem = gid & 16383;
  int stage = rem >> 13, bb = (rem >> 9) & 15, c = rem & 511;
  const float* w = stage ? f2w1 : f1w1;
  float acc = 0.f;
  if (half == 0) acc = stage ? f2b1[c] : f1b1[c];
  const float* th = theta + bb * 512 + half * 256;
  const float* wp = w + (size_t)(half * 256) * 512 + c;
  #pragma unroll 8
  for (int k = 0; k < 256; ++k) acc += th[k] * wp[(size_t)k * 512];
  atomicAdd(&h1b[rem], acc);
}

// =====================================================================
// fold3: M=64-row blocks (padded to 32448 = 507*64), N=512 in two 256-col
// passes, BK=64. m97-style 2-barrier K-loop: A computed to LDS, B staged
// via global_load_lds(16B). 8 waves = 2M x 4N, wave tile 32x64 per pass.
// launch_bounds (512,2): (512,4) capped VGPRs at 64 -> spill (R4 counters)
// =====================================================================
struct Fold3Smem {
  unsigned short sB[2048 * 8];   // 32 KB  chunk(k8,col) at (k8*256+col)*16B
  unsigned short sA[512 * 8];    // 8 KB   chunk(k8,row) at (k8*64+row)*16B
  float h1bL[2][2][512];         // 8 KB   [stage][b0/b1][c]
  float w1eL[3][512];            // 6 KB
  float b2s[512];                // 2 KB
  float w3s[3][512];             // 6 KB
  float red[8][32][3];           // 3 KB
  float ext[64][5];              // 1.25 KB (pad 5 -> conflict-free)
  int   rowb[64];
};

template <int ST>
__device__ __forceinline__ void fold3_stage(Fold3Smem& S, int t, int r0,
    const unsigned short* __restrict__ wst,   // 512x512 bf16 [col][k]
    const float* __restrict__ w1, const float* __restrict__ b2,
    const float* __restrict__ w3, const float* __restrict__ b3,
    float* __restrict__ out_pc)
{
  constexpr int NE = ST ? 3 : 2;
  const int wv = t >> 6, lane = t & 63, l15 = lane & 15, hi = lane >> 4;
  const int wm = wv >> 2, wn = wv & 3;

  // stage-constant LDS loads (one element per thread)
  {
    const int c = t;   // 512 threads == 512 cols
    S.w1eL[0][c] = w1[(size_t)512 * 512 + c];
    S.w1eL[1][c] = w1[(size_t)513 * 512 + c];
    if (NE == 3) S.w1eL[2][c] = w1[(size_t)514 * 512 + c];
    S.b2s[c] = b2[c];
    S.w3s[0][c] = w3[c * 3 + 0];
    S.w3s[1][c] = w3[c * 3 + 1];
    S.w3s[2][c] = w3[c * 3 + 2];
  }
  __syncthreads();

  float p[2][4][3];
  #pragma unroll
  for (int m = 0; m < 2; ++m)
    #pragma unroll
    for (int r = 0; r < 4; ++r)
      #pragma unroll
      for (int jj = 0; jj < 3; ++jj) p[m][r][jj] = 0.f;

  const int k8a = t >> 6, arow = t & 63;       // A-compute assignment
  const int sl = S.rowb[arow];

  for (int pass = 0; pass < 2; ++pass) {
    f32x4 acc[2][4];
    #pragma unroll
    for (int m = 0; m < 2; ++m)
      #pragma unroll
      for (int n = 0; n < 4; ++n) acc[m][n] = (f32x4){0.f, 0.f, 0.f, 0.f};

    const unsigned short* wB = wst + (size_t)(pass * 256) * 512;

    for (int kt = 0; kt < 8; ++kt) {
      const int kk = kt * 64;
      // ---- A-compute: thread -> chunk (k8a, arow), 8 values c = kk+k8a*8+j
      {
        const int cb = kk + k8a * 8;
        const float e0 = S.ext[arow][0], e1 = S.ext[arow][1];
        const float4 hb0 = *(const float4*)&S.h1bL[ST][sl][cb];
        const float4 hb1 = *(const float4*)&S.h1bL[ST][sl][cb + 4];
        const float4 wa0 = *(const float4*)&S.w1eL[0][cb];
        const float4 wa1 = *(const float4*)&S.w1eL[0][cb + 4];
        const float4 wb0 = *(const float4*)&S.w1eL[1][cb];
        const float4 wb1 = *(const float4*)&S.w1eL[1][cb + 4];
        float v0 = hb0.x + e0 * wa0.x + e1 * wb0.x;
        float v1 = hb0.y + e0 * wa0.y + e1 * wb0.y;
        float v2 = hb0.z + e0 * wa0.z + e1 * wb0.z;
        float v3 = hb0.w + e0 * wa0.w + e1 * wb0.w;
        float v4 = hb1.x + e0 * wa1.x + e1 * wb1.x;
        float v5 = hb1.y + e0 * wa1.y + e1 * wb1.y;
        float v6 = hb1.z + e0 * wa1.z + e1 * wb1.z;
        float v7 = hb1.w + e0 * wa1.w + e1 * wb1.w;
        if (NE == 3) {
          const float e2 = S.ext[arow][2];
          const float4 wc0 = *(const float4*)&S.w1eL[2][cb];
          const float4 wc1 = *(const float4*)&S.w1eL[2][cb + 4];
          v0 += e2 * wc0.x; v1 += e2 * wc0.y; v2 += e2 * wc0.z; v3 += e2 * wc0.w;
          v4 += e2 * wc1.x; v5 += e2 * wc1.y; v6 += e2 * wc1.z; v7 += e2 * wc1.w;
        }
        int4 pk;
        pk.x = (unsigned)f2bf(fmaxf(v0, 0.f)) | ((unsigned)f2bf(fmaxf(v1, 0.f)) << 16);
        pk.y = (unsigned)f2bf(fmaxf(v2, 0.f)) | ((unsigned)f2bf(fmaxf(v3, 0.f)) << 16);
        pk.z = (unsigned)f2bf(fmaxf(v4, 0.f)) | ((unsigned)f2bf(fmaxf(v5, 0.f)) << 16);
        pk.w = (unsigned)f2bf(fmaxf(v6, 0.f)) | ((unsigned)f2bf(fmaxf(v7, 0.f)) << 16);
        *(int4*)&S.sA[(size_t)t * 8] = pk;
      }
      // ---- B-stage: 4 wave-issues of 1 KB (global_load_lds width 16)
      #pragma unroll
      for (int i = 0; i < 4; ++i) {
        const int cidx = i * 8 + wv;                 // 0..31
        const int k8 = cidx >> 2, colb = (cidx & 3) * 64;
        const unsigned short* g = wB + (size_t)(colb + lane) * 512 + kk + k8 * 8;
        gload_lds16(g, &S.sB[(size_t)cidx * 512]);   // 512 ushorts = 1 KB
      }
      __syncthreads();
      // ---- MFMA: 16 per wave
      #pragma unroll
      for (int ks = 0; ks < 2; ++ks) {
        const int k8 = ks * 4 + hi;
        const bf16x8 a0 = *(const bf16x8*)&S.sA[(size_t)(k8 * 64 + wm * 32 + l15) * 8];
        const bf16x8 a1 = *(const bf16x8*)&S.sA[(size_t)(k8 * 64 + wm * 32 + 16 + l15) * 8];
        #pragma unroll
        for (int n = 0; n < 4; ++n) {
          const bf16x8 bv = *(const bf16x8*)&S.sB[(size_t)(k8 * 256 + wn * 64 + 16 * n + l15) * 8];
          acc[0][n] = __builtin_amdgcn_mfma_f32_16x16x32_bf16(a0, bv, acc[0][n], 0, 0, 0);
          acc[1][n] = __builtin_amdgcn_mfma_f32_16x16x32_bf16(a1, bv, acc[1][n], 0, 0, 0);
        }
      }
      __syncthreads();
    }

    // ---- layer-3 partials from acc (stays in registers across passes)
    #pragma unroll
    for (int n = 0; n < 4; ++n) {
      const int colG = pass * 256 + wn * 64 + 16 * n + l15;
      const float b2c = S.b2s[colG];
      const float w30 = S.w3s[0][colG], w31 = S.w3s[1][colG], w32 = S.w3s[2][colG];
      #pragma unroll
      for (int m = 0; m < 2; ++m)
        #pragma unroll
        for (int r = 0; r < 4; ++r) {
          const float h = fmaxf(acc[m][n][r] + b2c, 0.f);
          p[m][r][0] += h * w30; p[m][r][1] += h * w31; p[m][r][2] += h * w32;
        }
    }
  }

  // ---- reduce p over the 16 col-lanes
  #pragma unroll
  for (int m = 0; m < 2; ++m)
    #pragma unroll
    for (int r = 0; r < 4; ++r)
      #pragma unroll
      for (int jj = 0; jj < 3; ++jj) {
        float v = p[m][r][jj];
        v += __shfl_xor(v, 1); v += __shfl_xor(v, 2);
        v += __shfl_xor(v, 4); v += __shfl_xor(v, 8);
        p[m][r][jj] = v;
      }
  if (l15 == 0) {
    #pragma unroll
    for (int m = 0; m < 2; ++m)
      #pragma unroll
      for (int r = 0; r < 4; ++r) {
        const int rl = 16 * m + hi * 4 + r;   // 0..31 within wave rows
        S.red[wv][rl][0] = p[m][r][0];
        S.red[wv][rl][1] = p[m][r][1];
        S.red[wv][rl][2] = p[m][r][2];
      }
  }
  __syncthreads();

  if (t < 192) {
    const int row = t / 3, jj = t - (t / 3) * 3;
    const int wg = (row >> 5) * 4, rl = row & 31;
    float v = b3[jj] + S.red[wg][rl][jj] + S.red[wg + 1][rl][jj]
                     + S.red[wg + 2][rl][jj] + S.red[wg + 3][rl][jj];
    if (ST == 0) S.ext[row][jj] = v;
    else if (r0 + row < NROWS) out_pc[(size_t)(r0 + row) * 3 + jj] = v;
  }
  __syncthreads();
}

__global__ __launch_bounds__(512, 2) void fold3_kernel(
    const float* __restrict__ grid2, const float* __restrict__ h1b,
    const unsigned short* __restrict__ w2T,
    const float* __restrict__ f1w1, const float* __restrict__ f1b2,
    const float* __restrict__ f1w3, const float* __restrict__ f1b3,
    const float* __restrict__ f2w1, const float* __restrict__ f2b2,
    const float* __restrict__ f2w3, const float* __restrict__ f2b3,
    float* __restrict__ out_pc)
{
  __shared__ Fold3Smem S;
  const int t = threadIdx.x;
  const int r0 = blockIdx.x * 64;
  const int b0 = min(r0 / MQ, NBATCH - 1);
  const int b1 = min(b0 + 1, NBATCH - 1);

  if (t < 64) {
    const int r = r0 + t;
    const int bb = min(r / MQ, NBATCH - 1);
    S.rowb[t] = bb - b0;
    const int m = min(r - bb * MQ, MQ - 1);
    S.ext[t][0] = grid2[m * 2 + 0];
    S.ext[t][1] = grid2[m * 2 + 1];
    S.ext[t][2] = 0.f;
  }
  for (int i = t; i < 2048; i += 512) {
    const int st = i >> 10, sl = (i >> 9) & 1, c = i & 511;
    S.h1bL[st][sl][c] = h1b[st * 8192 + (sl ? b1 : b0) * 512 + c];
  }
  __syncthreads();

  fold3_stage<0>(S, t, r0, w2T,          f1w1, f1b2, f1w3, f1b3, nullptr);
  fold3_stage<1>(S, t, r0, w2T + 262144, f2w1, f2b2, f2w3, f2b3, out_pc);
}

// =====================================================================
// Chamfer A / B (unchanged, passed)
// =====================================================================
__global__ __launch_bounds__(256) void chamA_kernel(const float* __restrict__ pts,
                                                    const float* __restrict__ pc,
                                                    float* __restrict__ lacc)
{
  __shared__ float sbx[2048], sby[2048], sbz[2048];
  const int t = threadIdx.x;
  const int b = blockIdx.x >> 5;
  const int n0 = (blockIdx.x & 31) << 6;
  const float* pcb = pc + (size_t)b * (MQ * 3);
  for (int i = t; i < MQ * 3; i += 256) {
    float v = pcb[i];
    int m = i / 3, j = i - m * 3;
    if (j == 0) sbx[m] = v; else if (j == 1) sby[m] = v; else sbz[m] = v;
  }
  for (int i = MQ + t; i < 2048; i += 256) { sbx[i] = 1e30f; sby[i] = 1e30f; sbz[i] = 1e30f; }
  __syncthreads();

  const int pid = t >> 4, q = t & 15;
  float ax[4], ay[4], az[4], mn[4];
  #pragma unroll
  for (int j = 0; j < 4; ++j) {
    const int n = n0 + pid * 4 + j;
    float4 P = *(const float4*)(pts + ((size_t)b * NPTS + n) * 4);
    ax[j] = P.x; ay[j] = P.y; az[j] = P.z + P.w; mn[j] = 1e30f;
  }
  #pragma unroll 4
  for (int i = 0; i < 32; ++i) {
    const int m4 = q * 4 + i * 64;
    float4 bx = *(const float4*)&sbx[m4];
    float4 by = *(const float4*)&sby[m4];
    float4 bz = *(const float4*)&sbz[m4];
    #pragma unroll
    for (int j = 0; j < 4; ++j) {
      float d0, dx, dy, dz;
      dx = ax[j] - bx.x; dy = ay[j] - by.x; dz = az[j] - bz.x; d0 = dx*dx + dy*dy + dz*dz; mn[j] = fminf(mn[j], d0);
      dx = ax[j] - bx.y; dy = ay[j] - by.y; dz = az[j] - bz.y; d0 = dx*dx + dy*dy + dz*dz; mn[j] = fminf(mn[j], d0);
      dx = ax[j] - bx.z; dy = ay[j] - by.z; dz = az[j] - bz.z; d0 = dx*dx + dy*dy + dz*dz; mn[j] = fminf(mn[j], d0);
      dx = ax[j] - bx.w; dy = ay[j] - by.w; dz = az[j] - bz.w; d0 = dx*dx + dy*dy + dz*dz; mn[j] = fminf(mn[j], d0);
    }
  }
  #pragma unroll
  for (int j = 0; j < 4; ++j) {
    mn[j] = fminf(mn[j], __shfl_xor(mn[j], 1));
    mn[j] = fminf(mn[j], __shfl_xor(mn[j], 2));
    mn[j] = fminf(mn[j], __shfl_xor(mn[j], 4));
    mn[j] = fminf(mn[j], __shfl_xor(mn[j], 8));
  }
  float v = (q == 0) ? (mn[0] + mn[1] + mn[2] + mn[3]) : 0.f;
  v += __shfl_xor(v, 16); v += __shfl_xor(v, 32);
  if ((t & 63) == 0) atomicAdd(lacc, v);
}

__global__ __launch_bounds__(256) void chamB_kernel(const float* __restrict__ pts,
                                                    const float* __restrict__ pc,
                                                    float* __restrict__ lacc)
{
  __shared__ float sax[2048], say[2048], saz[2048];
  const int t = threadIdx.x;
  const int b = blockIdx.x >> 5;
  const int m0 = (blockIdx.x & 31) << 6;
  for (int i = t; i < NPTS; i += 256) {
    float4 pp = *(const float4*)(pts + ((size_t)b * NPTS + i) * 4);
    sax[i] = pp.x; say[i] = pp.y; saz[i] = pp.z + pp.w;
  }
  __syncthreads();

  const int pid = t >> 4, q = t & 15;
  float bx[4], by[4], bz[4], mn[4];
  bool vld[4];
  #pragma unroll
  for (int j = 0; j < 4; ++j) {
    const int m = m0 + pid * 4 + j;
    vld[j] = (m < MQ);
    const int mc = vld[j] ? m : (MQ - 1);
    bx[j] = pc[(size_t)b * (MQ * 3) + mc * 3 + 0];
    by[j] = pc[(size_t)b * (MQ * 3) + mc * 3 + 1];
    bz[j] = pc[(size_t)b * (MQ * 3) + mc * 3 + 2];
    mn[j] = 1e30f;
  }
  #pragma unroll 4
  for (int i = 0; i < 32; ++i) {
    const int n4 = q * 4 + i * 64;
    float4 axv = *(const float4*)&sax[n4];
    float4 ayv = *(const float4*)&say[n4];
    float4 azv = *(const float4*)&saz[n4];
    #pragma unroll
    for (int j = 0; j < 4; ++j) {
      float d0, dx, dy, dz;
      dx = axv.x - bx[j]; dy = ayv.x - by[j]; dz = azv.x - bz[j]; d0 = dx*dx + dy*dy + dz*dz; mn[j] = fminf(mn[j], d0);
      dx = axv.y - bx[j]; dy = ayv.y - by[j]; dz = azv.y - bz[j]; d0 = dx*dx + dy*dy + dz*dz; mn[j] = fminf(mn[j], d0);
      dx = axv.z - bx[j]; dy = ayv.z - by[j]; dz = azv.z - bz[j]; d0 = dx*dx + dy*dy + dz*dz; mn[j] = fminf(mn[j], d0);
      dx = axv.w - bx[j]; dy = ayv.w - by[j]; dz = azv.w - bz[j]; d0 = dx*dx + dy*dy + dz*dz; mn[j] = fminf(mn[j], d0);
    }
  }
  #pragma unroll
  for (int j = 0; j < 4; ++j) {
    mn[j] = fminf(mn[j], __shfl_xor(mn[j], 1));
    mn[j] = fminf(mn[j], __shfl_xor(mn[j], 2));
    mn[j] = fminf(mn[j], __shfl_xor(mn[j], 4));
    mn[j] = fminf(mn[j], __shfl_xor(mn[j], 8));
  }
  float v = 0.f;
  if (q == 0) {
    #pragma unroll
    for (int j = 0; j < 4; ++j) if (vld[j]) v += mn[j];
  }
  v += __shfl_xor(v, 16); v += __shfl_xor(v, 32);
  if ((t & 63) == 0) atomicAdd(lacc + 1, v);
}

__global__ void fin_kernel(const float* __restrict__ lacc, float* __restrict__ loss) {
  if (threadIdx.x == 0 && blockIdx.x == 0)
    loss[0] = lacc[0] * (1.0f / (NBATCH * NPTS)) + lacc[1] * (1.0f / (NBATCH * MQ));
}

// =====================================================================
extern "C" void kernel_launch(void* const* d_in, const int* in_sizes, int n_in,
                              void* d_out, int out_size, void* d_ws, size_t ws_size,
                              hipStream_t stream) {
  const float* pts  = (const float*)d_in[0];
  const float* ew1  = (const float*)d_in[1];
  const float* eb1  = (const float*)d_in[2];
  const float* ew2  = (const float*)d_in[3];
  const float* eb2  = (const float*)d_in[4];
  const float* ew3  = (const float*)d_in[5];
  const float* eb3  = (const float*)d_in[6];
  const float* f1w1 = (const float*)d_in[7];
  const float* f1b1 = (const float*)d_in[8];
  const float* f1w2 = (const float*)d_in[9];
  const float* f1b2 = (const float*)d_in[10];
  const float* f1w3 = (const float*)d_in[11];
  const float* f1b3 = (const float*)d_in[12];
  const float* f2w1 = (const float*)d_in[13];
  const float* f2b1 = (const float*)d_in[14];
  const float* f2w2 = (const float*)d_in[15];
  const float* f2b2 = (const float*)d_in[16];
  const float* f2w3 = (const float*)d_in[17];
  const float* f2b3 = (const float*)d_in[18];
  const float* grid2= (const float*)d_in[19];

  float* out = (float*)d_out;
  unsigned* keys       = (unsigned*)d_ws;                              // 32768 B
  float* lacc          = (float*)((char*)d_ws + 32768);                // -> 33024
  float* h1b           = (float*)((char*)d_ws + 33024);                // 65536 B -> 98560
  unsigned short* w2T  = (unsigned short*)((char*)d_ws + 98560);       // 1 MB -> 1147136
  unsigned short* ew2T = (unsigned short*)((char*)d_ws + 1147136);     // 16 KB
  unsigned short* ew3T = (unsigned short*)((char*)d_ws + 1163520);     // 128 KB

  hipMemsetAsync(d_ws, 0, 98560, stream);   // keys + lacc + h1b

  tconv_kernel<<<584, 256, 0, stream>>>(f1w2, f2w2, ew2, ew3, w2T, ew2T, ew3T);
  enc2_kernel<<<512, 512, 0, stream>>>(pts, ew1, eb1, ew2T, eb2, ew3T, eb3, keys);
  decode_kernel<<<32, 256, 0, stream>>>(keys, out);                    // theta
  h1base_kernel<<<128, 256, 0, stream>>>(out, f1w1, f1b1, f2w1, f2b1, h1b);
  fold3_kernel<<<507, 512, 0, stream>>>(grid2, h1b, w2T,
                                        f1w1, f1b2, f1w3, f1b3,
                                        f2w1, f2b2, f2w3, f2b3,
                                        out + 8192);                   // pc_out
  chamA_kernel<<<512, 256, 0, stream>>>(pts, out + 8192, lacc);
  chamB_kernel<<<512, 256, 0, stream>>>(pts, out + 8192, lacc);
  fin_kernel<<<1, 64, 0, stream>>>(lacc, out + 8192 + 97200);          // loss
}

// Round 6
// 354.196 us; speedup vs baseline: 1.1332x; 1.1332x over previous
//
#include <hip/hip_runtime.h>

#define NBATCH 16
#define NPTS   2048
#define MQ     2025
#define CWDIM  512
#define NROWS  32400

typedef __attribute__((ext_vector_type(8))) short bf16x8;
typedef __attribute__((ext_vector_type(4))) float f32x4;
typedef unsigned int as1_u32 __attribute__((address_space(1)));
typedef unsigned int as3_u32 __attribute__((address_space(3)));

// ---------- helpers ----------
__device__ __forceinline__ unsigned fkey(float f) {
  unsigned u = __float_as_uint(f);
  return (u & 0x80000000u) ? ~u : (u | 0x80000000u);
}
__device__ __forceinline__ float funkey(unsigned u) {
  unsigned v = (u & 0x80000000u) ? (u ^ 0x80000000u) : ~u;
  return __uint_as_float(v);
}
__device__ __forceinline__ unsigned short f2bf(float f) {  // RNE f32->bf16
  unsigned u = __float_as_uint(f);
  u = (u + 0x7FFFu + ((u >> 16) & 1u)) >> 16;
  return (unsigned short)u;
}
__device__ __forceinline__ void gload_lds16(const void* g, void* l) {
  __builtin_amdgcn_global_load_lds((const as1_u32*)g, (as3_u32*)l, 16, 0, 0);
}

// =====================================================================
// tconv: transpose+convert encoder weights only (ew2 64x128, ew3 128x512)
// =====================================================================
__global__ __launch_bounds__(256) void tconv_kernel(
    const float* __restrict__ ew2, const float* __restrict__ ew3,
    unsigned short* __restrict__ ew2T, unsigned short* __restrict__ ew3T)
{
  __shared__ float tile[32][33];
  const int blk = blockIdx.x;
  const float* src; unsigned short* dst; int K, N, tidx;
  if (blk < 8) { src = ew2; dst = ew2T; K = 64;  N = 128; tidx = blk; }
  else         { src = ew3; dst = ew3T; K = 128; N = 512; tidx = blk - 8; }
  const int ntn = N >> 5;
  const int kt = tidx / ntn, nt = tidx - kt * ntn;
  const int tx = threadIdx.x & 31, ty = threadIdx.x >> 5;
  #pragma unroll
  for (int j = 0; j < 4; ++j)
    tile[ty + 8 * j][tx] = src[(size_t)(kt * 32 + ty + 8 * j) * N + nt * 32 + tx];
  __syncthreads();
  #pragma unroll
  for (int j = 0; j < 4; ++j)
    dst[(size_t)(nt * 32 + ty + 8 * j) * K + kt * 32 + tx] = f2bf(tile[tx][ty + 8 * j]);
}

// =====================================================================
// w2chunk: fold layer-2 weights -> K-octet-major bf16 chunks
// w2C[stage][(ko*512+col)*8 + j] = bf16(w2[ko*8+j][col]),  ko in [0,64)
// =====================================================================
__global__ __launch_bounds__(256) void w2chunk_kernel(
    const float* __restrict__ f1w2, const float* __restrict__ f2w2,
    unsigned short* __restrict__ w2C)
{
  const int gid = blockIdx.x * 256 + threadIdx.x;   // 65536
  const int s = gid >> 15;
  const int rem = gid & 32767;                      // ko*512 + col
  const int col = rem & 511, ko = rem >> 9;
  const float* src = s ? f2w2 : f1w2;
  unsigned short tmp[8];
  #pragma unroll
  for (int j = 0; j < 8; ++j)
    tmp[j] = f2bf(src[(size_t)(ko * 8 + j) * 512 + col]);
  int4 pk;
  pk.x = (int)((unsigned)tmp[0] | ((unsigned)tmp[1] << 16));
  pk.y = (int)((unsigned)tmp[2] | ((unsigned)tmp[3] << 16));
  pk.z = (int)((unsigned)tmp[4] | ((unsigned)tmp[5] << 16));
  pk.w = (int)((unsigned)tmp[6] | ((unsigned)tmp[7] << 16));
  *(int4*)&w2C[(size_t)s * 262144 + (size_t)rem * 8] = pk;
}

// =====================================================================
// Encoder (MFMA): block = 64 points, 512 thr = 8 waves. (unchanged, passed)
// =====================================================================
__global__ __launch_bounds__(512, 2) void enc2_kernel(
    const float* __restrict__ pts,
    const float* __restrict__ ew1, const float* __restrict__ eb1,
    const unsigned short* __restrict__ ew2T, const float* __restrict__ eb2,
    const unsigned short* __restrict__ ew3T, const float* __restrict__ eb3,
    unsigned* __restrict__ keys)
{
  __shared__ unsigned short h1s[64 * 64];
  __shared__ unsigned short h2s[64 * 128];
  __shared__ float s_pts[64][4];
  const int t = threadIdx.x;
  const int b = blockIdx.x >> 5, p0 = (blockIdx.x & 31) << 6;
  if (t < 64)
    *(float4*)&s_pts[t][0] = *(const float4*)(pts + ((size_t)b * NPTS + p0 + t) * 4);
  __syncthreads();

  {
    const int c = t & 63;
    const float w0 = ew1[c], w1 = ew1[64 + c], w2 = ew1[128 + c], w3 = ew1[192 + c];
    const float bb = eb1[c];
    #pragma unroll
    for (int i = 0; i < 8; ++i) {
      const int p = i * 8 + (t >> 6);
      float acc = bb + s_pts[p][0] * w0 + s_pts[p][1] * w1 + s_pts[p][2] * w2 + s_pts[p][3] * w3;
      unsigned byte = ((unsigned)p << 7) + ((unsigned)c << 1);
      byte ^= ((unsigned)(p & 7)) << 4;
      h1s[byte >> 1] = f2bf(fmaxf(acc, 0.f));
    }
  }
  __syncthreads();

  const int wv = t >> 6, lane = t & 63, l15 = lane & 15, hi = lane >> 4;

  {
    f32x4 acc[4];
    #pragma unroll
    for (int m = 0; m < 4; ++m) acc[m] = (f32x4){0.f, 0.f, 0.f, 0.f};
    const int col = 16 * wv + l15;
    #pragma unroll
    for (int kk = 0; kk < 64; kk += 32) {
      bf16x8 bv = *(const bf16x8*)(ew2T + (size_t)col * 64 + kk + hi * 8);
      #pragma unroll
      for (int m = 0; m < 4; ++m) {
        const int row = 16 * m + l15;
        unsigned byte = ((unsigned)row << 7) + ((unsigned)((kk + hi * 8)) << 1);
        byte ^= ((unsigned)(row & 7)) << 4;
        bf16x8 av = *(const bf16x8*)&h1s[byte >> 1];
        acc[m] = __builtin_amdgcn_mfma_f32_16x16x32_bf16(av, bv, acc[m], 0, 0, 0);
      }
    }
    const float b2c = eb2[col];
    #pragma unroll
    for (int m = 0; m < 4; ++m)
      #pragma unroll
      for (int r = 0; r < 4; ++r) {
        const int row = 16 * m + hi * 4 + r;
        unsigned byte = ((unsigned)row << 8) + ((unsigned)col << 1);
        byte ^= ((unsigned)(row & 7)) << 4;
        h2s[byte >> 1] = f2bf(fmaxf(acc[m][r] + b2c, 0.f));
      }
  }
  __syncthreads();

  {
    f32x4 acc[4][4];
    #pragma unroll
    for (int m = 0; m < 4; ++m)
      #pragma unroll
      for (int n = 0; n < 4; ++n) acc[m][n] = (f32x4){0.f, 0.f, 0.f, 0.f};
    #pragma unroll
    for (int kk = 0; kk < 128; kk += 32) {
      bf16x8 av[4];
      #pragma unroll
      for (int m = 0; m < 4; ++m) {
        const int row = 16 * m + l15;
        unsigned byte = ((unsigned)row << 8) + ((unsigned)(kk + hi * 8) << 1);
        byte ^= ((unsigned)(row & 7)) << 4;
        av[m] = *(const bf16x8*)&h2s[byte >> 1];
      }
      #pragma unroll
      for (int n = 0; n < 4; ++n) {
        const int col = 64 * wv + 16 * n + l15;
        bf16x8 bv = *(const bf16x8*)(ew3T + (size_t)col * 128 + kk + hi * 8);
        #pragma unroll
        for (int m = 0; m < 4; ++m)
          acc[m][n] = __builtin_amdgcn_mfma_f32_16x16x32_bf16(av[m], bv, acc[m][n], 0, 0, 0);
      }
    }
    #pragma unroll
    for (int n = 0; n < 4; ++n) {
      const int col = 64 * wv + 16 * n + l15;
      float mx = -1e30f;
      #pragma unroll
      for (int m = 0; m < 4; ++m)
        #pragma unroll
        for (int r = 0; r < 4; ++r) mx = fmaxf(mx, acc[m][n][r]);
      mx = fmaxf(mx, __shfl_xor(mx, 16));
      mx = fmaxf(mx, __shfl_xor(mx, 32));
      if (hi == 0) atomicMax(&keys[b * CWDIM + col], fkey(mx + eb3[col]));
    }
  }
}

__global__ __launch_bounds__(256) void decode_kernel(const unsigned* __restrict__ keys,
                                                     float* __restrict__ theta) {
  int i = blockIdx.x * 256 + threadIdx.x;
  theta[i] = funkey(keys[i]);
}

// =====================================================================
// h1base split-K x2: atomicAdd partials (h1b pre-zeroed by memset)
// =====================================================================
__global__ __launch_bounds__(256) void h1base_kernel(
    const float* __restrict__ theta,
    const float* __restrict__ f1w1, const float* __restrict__ f1b1,
    const float* __restrict__ f2w1, const float* __restrict__ f2b1,
    float* __restrict__ h1b)
{
  int gid = blockIdx.x * 256 + threadIdx.x;   // 32768
  int half = gid >> 14;
  int rem = gid & 16383;
  int stage = rem >> 13, bb = (rem >> 9) & 15, c = rem & 511;
  const float* w = stage ? f2w1 : f1w1;
  float acc = 0.f;
  if (half == 0) acc = stage ? f2b1[c] : f1b1[c];
  const float* th = theta + bb * 512 + half * 256;
  const float* wp = w + (size_t)(half * 256) * 512 + c;
  #pragma unroll 8
  for (int k = 0; k < 256; ++k) acc += th[k] * wp[(size_t)k * 512];
  atomicAdd(&h1b[rem], acc);
}

// =====================================================================
// fold4: BM=64 (507 blocks), N=512 in 2 passes of 256, BK=32 double-buffered.
// sA (full-K, built once/stage, conflict-free [ko][row][8]) +
// contiguous-source gload_lds B staging + 1 barrier per kt.
// =====================================================================
struct Fold4Smem {
  unsigned short sA[64 * 64 * 8];      // 64 KB  [ko][row][8]
  unsigned short sB[2][4 * 256 * 8];   // 32 KB  [buf][kol][col][8]
  float b2s[512];                      // 2 KB
  float w3s[3][512];                   // 6 KB
  float red[8][32][3];                 // 3 KB
  float ext[64][4];                    // 1 KB
  int   rowbb[64];                     // 256 B
};

#define STAGE4(buf, ktv)                                                        \
  do {                                                                          \
    _Pragma("unroll")                                                           \
    for (int s_ = 0; s_ < 2; ++s_) {                                            \
      const int idx_ = wv * 2 + s_;                                             \
      const int kol_ = idx_ >> 2, cb_ = idx_ & 3;                               \
      const unsigned short* g_ = wst +                                          \
          ((size_t)((ktv) * 4 + kol_) * 512 + pass * 256 + cb_ * 64 + lane) * 8;\
      gload_lds16(g_, &S.sB[buf][(unsigned)(kol_ * 256 + cb_ * 64) * 8]);       \
    }                                                                           \
  } while (0)

#define MFMA4(buf, ktv)                                                         \
  do {                                                                          \
    const unsigned ab_ = ((unsigned)((ktv) * 4 + hi) * 64 + wm * 32 + l15) * 8; \
    bf16x8 a0_ = *(const bf16x8*)&S.sA[ab_];                                    \
    bf16x8 a1_ = *(const bf16x8*)&S.sA[ab_ + 128];                              \
    _Pragma("unroll")                                                           \
    for (int n_ = 0; n_ < 4; ++n_) {                                            \
      bf16x8 bv_ = *(const bf16x8*)                                             \
          &S.sB[buf][(unsigned)(hi * 256 + wn * 64 + 16 * n_ + l15) * 8];       \
      acc[0][n_] = __builtin_amdgcn_mfma_f32_16x16x32_bf16(a0_, bv_, acc[0][n_], 0, 0, 0); \
      acc[1][n_] = __builtin_amdgcn_mfma_f32_16x16x32_bf16(a1_, bv_, acc[1][n_], 0, 0, 0); \
    }                                                                           \
  } while (0)

template <int ST>
__device__ __forceinline__ void fold4_stage(Fold4Smem& S, int t, int r0,
    const float* __restrict__ h1bg,
    const float* __restrict__ w1,
    const unsigned short* __restrict__ wst,   // chunked [ko][col][8]
    const float* __restrict__ b2, const float* __restrict__ w3,
    const float* __restrict__ b3, float* __restrict__ out_pc)
{
  constexpr int NE = ST ? 3 : 2;
  const int wv = t >> 6, lane = t & 63, l15 = lane & 15, hi = lane >> 4;
  const int wm = wv >> 2, wn = wv & 3;

  // stage constants (512 threads cover 512 cols)
  S.b2s[t] = b2[t];
  S.w3s[0][t] = w3[t * 3 + 0];
  S.w3s[1][t] = w3[t * 3 + 1];
  S.w3s[2][t] = w3[t * 3 + 2];
  __syncthreads();   // also orders prev-stage ext writes -> A-build reads

  // ---- A-build: full 64x512 tile -> sA, once per stage
  {
    const int row = t & 63;
    const int bb = S.rowbb[row];
    const float e0 = S.ext[row][0], e1 = S.ext[row][1];
    float e2 = 0.f;
    if (NE == 3) e2 = S.ext[row][2];
    const float* hb  = h1bg + ST * 8192 + bb * 512;
    const float* wr0 = w1 + (size_t)512 * 512;
    const float* wr1 = w1 + (size_t)513 * 512;
    const float* wr2 = w1 + (size_t)514 * 512;
    #pragma unroll
    for (int i = 0; i < 8; ++i) {
      const int ko = (t >> 6) * 8 + i;
      const int c0 = ko * 8;
      float v[8];
      #pragma unroll
      for (int hf = 0; hf < 2; ++hf) {
        float4 h = *(const float4*)(hb + c0 + hf * 4);
        float4 a = *(const float4*)(wr0 + c0 + hf * 4);
        float4 bq = *(const float4*)(wr1 + c0 + hf * 4);
        v[hf * 4 + 0] = h.x + e0 * a.x + e1 * bq.x;
        v[hf * 4 + 1] = h.y + e0 * a.y + e1 * bq.y;
        v[hf * 4 + 2] = h.z + e0 * a.z + e1 * bq.z;
        v[hf * 4 + 3] = h.w + e0 * a.w + e1 * bq.w;
        if (NE == 3) {
          float4 cq = *(const float4*)(wr2 + c0 + hf * 4);
          v[hf * 4 + 0] += e2 * cq.x; v[hf * 4 + 1] += e2 * cq.y;
          v[hf * 4 + 2] += e2 * cq.z; v[hf * 4 + 3] += e2 * cq.w;
        }
      }
      int4 pk;
      pk.x = (int)((unsigned)f2bf(fmaxf(v[0], 0.f)) | ((unsigned)f2bf(fmaxf(v[1], 0.f)) << 16));
      pk.y = (int)((unsigned)f2bf(fmaxf(v[2], 0.f)) | ((unsigned)f2bf(fmaxf(v[3], 0.f)) << 16));
      pk.z = (int)((unsigned)f2bf(fmaxf(v[4], 0.f)) | ((unsigned)f2bf(fmaxf(v[5], 0.f)) << 16));
      pk.w = (int)((unsigned)f2bf(fmaxf(v[6], 0.f)) | ((unsigned)f2bf(fmaxf(v[7], 0.f)) << 16));
      *(int4*)&S.sA[((unsigned)ko * 64 + row) * 8] = pk;
    }
  }
  __syncthreads();

  float p[2][4][3];
  #pragma unroll
  for (int m = 0; m < 2; ++m)
    #pragma unroll
    for (int r = 0; r < 4; ++r)
      #pragma unroll
      for (int jj = 0; jj < 3; ++jj) p[m][r][jj] = 0.f;

  for (int pass = 0; pass < 2; ++pass) {
    f32x4 acc[2][4];
    #pragma unroll
    for (int m = 0; m < 2; ++m)
      #pragma unroll
      for (int n = 0; n < 4; ++n) acc[m][n] = (f32x4){0.f, 0.f, 0.f, 0.f};

    STAGE4(0, 0);
    __syncthreads();

    #pragma unroll 1
    for (int kt = 0; kt < 16; kt += 2) {
      STAGE4(1, kt + 1);                 // kt+1 <= 15 always
      MFMA4(0, kt);
      __syncthreads();
      if (kt + 2 < 16) STAGE4(0, kt + 2);
      MFMA4(1, kt + 1);
      __syncthreads();
    }

    // layer-3 partials from acc (persist across passes)
    #pragma unroll
    for (int n = 0; n < 4; ++n) {
      const int colG = pass * 256 + wn * 64 + 16 * n + l15;
      const float b2c = S.b2s[colG];
      const float w30 = S.w3s[0][colG], w31 = S.w3s[1][colG], w32 = S.w3s[2][colG];
      #pragma unroll
      for (int m = 0; m < 2; ++m)
        #pragma unroll
        for (int r = 0; r < 4; ++r) {
          const float h = fmaxf(acc[m][n][r] + b2c, 0.f);
          p[m][r][0] += h * w30; p[m][r][1] += h * w31; p[m][r][2] += h * w32;
        }
    }
  }

  // reduce p over the 16 col-lanes
  #pragma unroll
  for (int m = 0; m < 2; ++m)
    #pragma unroll
    for (int r = 0; r < 4; ++r)
      #pragma unroll
      for (int jj = 0; jj < 3; ++jj) {
        float v = p[m][r][jj];
        v += __shfl_xor(v, 1); v += __shfl_xor(v, 2);
        v += __shfl_xor(v, 4); v += __shfl_xor(v, 8);
        p[m][r][jj] = v;
      }
  if (l15 == 0) {
    #pragma unroll
    for (int m = 0; m < 2; ++m)
      #pragma unroll
      for (int r = 0; r < 4; ++r) {
        const int rl = 16 * m + hi * 4 + r;
        S.red[wv][rl][0] = p[m][r][0];
        S.red[wv][rl][1] = p[m][r][1];
        S.red[wv][rl][2] = p[m][r][2];
      }
  }
  __syncthreads();

  if (t < 192) {
    const int row = t / 3, jj = t - (t / 3) * 3;
    const int wg = (row >> 5) * 4, rl = row & 31;
    float v = b3[jj] + S.red[wg][rl][jj] + S.red[wg + 1][rl][jj]
                     + S.red[wg + 2][rl][jj] + S.red[wg + 3][rl][jj];
    if (ST == 0) S.ext[row][jj] = v;
    else if (r0 + row < NROWS) out_pc[(size_t)(r0 + row) * 3 + jj] = v;
  }
  __syncthreads();
}

__global__ __launch_bounds__(512, 1) void fold4_kernel(
    const float* __restrict__ grid2, const float* __restrict__ h1b,
    const unsigned short* __restrict__ w2C,
    const float* __restrict__ f1w1, const float* __restrict__ f1b2,
    const float* __restrict__ f1w3, const float* __restrict__ f1b3,
    const float* __restrict__ f2w1, const float* __restrict__ f2b2,
    const float* __restrict__ f2w3, const float* __restrict__ f2b3,
    float* __restrict__ out_pc)
{
  __shared__ Fold4Smem S;
  const int t = threadIdx.x;
  const int r0 = blockIdx.x * 64;

  if (t < 64) {
    const int r = r0 + t;
    const int bb = min(r / MQ, NBATCH - 1);
    S.rowbb[t] = bb;
    const int m = min(r - bb * MQ, MQ - 1);
    S.ext[t][0] = grid2[m * 2 + 0];
    S.ext[t][1] = grid2[m * 2 + 1];
    S.ext[t][2] = 0.f;
    S.ext[t][3] = 0.f;
  }
  // stage-entry barrier inside fold4_stage orders these writes

  fold4_stage<0>(S, t, r0, h1b, f1w1, w2C,          f1b2, f1w3, f1b3, nullptr);
  fold4_stage<1>(S, t, r0, h1b, f2w1, w2C + 262144, f2b2, f2w3, f2b3, out_pc);
}

// =====================================================================
// Chamfer A / B (unchanged, passed)
// =====================================================================
__global__ __launch_bounds__(256) void chamA_kernel(const float* __restrict__ pts,
                                                    const float* __restrict__ pc,
                                                    float* __restrict__ lacc)
{
  __shared__ float sbx[2048], sby[2048], sbz[2048];
  const int t = threadIdx.x;
  const int b = blockIdx.x >> 5;
  const int n0 = (blockIdx.x & 31) << 6;
  const float* pcb = pc + (size_t)b * (MQ * 3);
  for (int i = t; i < MQ * 3; i += 256) {
    float v = pcb[i];
    int m = i / 3, j = i - m * 3;
    if (j == 0) sbx[m] = v; else if (j == 1) sby[m] = v; else sbz[m] = v;
  }
  for (int i = MQ + t; i < 2048; i += 256) { sbx[i] = 1e30f; sby[i] = 1e30f; sbz[i] = 1e30f; }
  __syncthreads();

  const int pid = t >> 4, q = t & 15;
  float ax[4], ay[4], az[4], mn[4];
  #pragma unroll
  for (int j = 0; j < 4; ++j) {
    const int n = n0 + pid * 4 + j;
    float4 P = *(const float4*)(pts + ((size_t)b * NPTS + n) * 4);
    ax[j] = P.x; ay[j] = P.y; az[j] = P.z + P.w; mn[j] = 1e30f;
  }
  #pragma unroll 4
  for (int i = 0; i < 32; ++i) {
    const int m4 = q * 4 + i * 64;
    float4 bx = *(const float4*)&sbx[m4];
    float4 by = *(const float4*)&sby[m4];
    float4 bz = *(const float4*)&sbz[m4];
    #pragma unroll
    for (int j = 0; j < 4; ++j) {
      float d0, dx, dy, dz;
      dx = ax[j] - bx.x; dy = ay[j] - by.x; dz = az[j] - bz.x; d0 = dx*dx + dy*dy + dz*dz; mn[j] = fminf(mn[j], d0);
      dx = ax[j] - bx.y; dy = ay[j] - by.y; dz = az[j] - bz.y; d0 = dx*dx + dy*dy + dz*dz; mn[j] = fminf(mn[j], d0);
      dx = ax[j] - bx.z; dy = ay[j] - by.z; dz = az[j] - bz.z; d0 = dx*dx + dy*dy + dz*dz; mn[j] = fminf(mn[j], d0);
      dx = ax[j] - bx.w; dy = ay[j] - by.w; dz = az[j] - bz.w; d0 = dx*dx + dy*dy + dz*dz; mn[j] = fminf(mn[j], d0);
    }
  }
  #pragma unroll
  for (int j = 0; j < 4; ++j) {
    mn[j] = fminf(mn[j], __shfl_xor(mn[j], 1));
    mn[j] = fminf(mn[j], __shfl_xor(mn[j], 2));
    mn[j] = fminf(mn[j], __shfl_xor(mn[j], 4));
    mn[j] = fminf(mn[j], __shfl_xor(mn[j], 8));
  }
  float v = (q == 0) ? (mn[0] + mn[1] + mn[2] + mn[3]) : 0.f;
  v += __shfl_xor(v, 16); v += __shfl_xor(v, 32);
  if ((t & 63) == 0) atomicAdd(lacc, v);
}

__global__ __launch_bounds__(256) void chamB_kernel(const float* __restrict__ pts,
                                                    const float* __restrict__ pc,
                                                    float* __restrict__ lacc)
{
  __shared__ float sax[2048], say[2048], saz[2048];
  const int t = threadIdx.x;
  const int b = blockIdx.x >> 5;
  const int m0 = (blockIdx.x & 31) << 6;
  for (int i = t; i < NPTS; i += 256) {
    float4 pp = *(const float4*)(pts + ((size_t)b * NPTS + i) * 4);
    sax[i] = pp.x; say[i] = pp.y; saz[i] = pp.z + pp.w;
  }
  __syncthreads();

  const int pid = t >> 4, q = t & 15;
  float bx[4], by[4], bz[4], mn[4];
  bool vld[4];
  #pragma unroll
  for (int j = 0; j < 4; ++j) {
    const int m = m0 + pid * 4 + j;
    vld[j] = (m < MQ);
    const int mc = vld[j] ? m : (MQ - 1);
    bx[j] = pc[(size_t)b * (MQ * 3) + mc * 3 + 0];
    by[j] = pc[(size_t)b * (MQ * 3) + mc * 3 + 1];
    bz[j] = pc[(size_t)b * (MQ * 3) + mc * 3 + 2];
    mn[j] = 1e30f;
  }
  #pragma unroll 4
  for (int i = 0; i < 32; ++i) {
    const int n4 = q * 4 + i * 64;
    float4 axv = *(const float4*)&sax[n4];
    float4 ayv = *(const float4*)&say[n4];
    float4 azv = *(const float4*)&saz[n4];
    #pragma unroll
    for (int j = 0; j < 4; ++j) {
      float d0, dx, dy, dz;
      dx = axv.x - bx[j]; dy = ayv.x - by[j]; dz = azv.x - bz[j]; d0 = dx*dx + dy*dy + dz*dz; mn[j] = fminf(mn[j], d0);
      dx = axv.y - bx[j]; dy = ayv.y - by[j]; dz = azv.y - bz[j]; d0 = dx*dx + dy*dy + dz*dz; mn[j] = fminf(mn[j], d0);
      dx = axv.z - bx[j]; dy = ayv.z - by[j]; dz = azv.z - bz[j]; d0 = dx*dx + dy*dy + dz*dz; mn[j] = fminf(mn[j], d0);
      dx = axv.w - bx[j]; dy = ayv.w - by[j]; dz = azv.w - bz[j]; d0 = dx*dx + dy*dy + dz*dz; mn[j] = fminf(mn[j], d0);
    }
  }
  #pragma unroll
  for (int j = 0; j < 4; ++j) {
    mn[j] = fminf(mn[j], __shfl_xor(mn[j], 1));
    mn[j] = fminf(mn[j], __shfl_xor(mn[j], 2));
    mn[j] = fminf(mn[j], __shfl_xor(mn[j], 4));
    mn[j] = fminf(mn[j], __shfl_xor(mn[j], 8));
  }
  float v = 0.f;
  if (q == 0) {
    #pragma unroll
    for (int j = 0; j < 4; ++j) if (vld[j]) v += mn[j];
  }
  v += __shfl_xor(v, 16); v += __shfl_xor(v, 32);
  if ((t & 63) == 0) atomicAdd(lacc + 1, v);
}

__global__ void fin_kernel(const float* __restrict__ lacc, float* __restrict__ loss) {
  if (threadIdx.x == 0 && blockIdx.x == 0)
    loss[0] = lacc[0] * (1.0f / (NBATCH * NPTS)) + lacc[1] * (1.0f / (NBATCH * MQ));
}

// =====================================================================
extern "C" void kernel_launch(void* const* d_in, const int* in_sizes, int n_in,
                              void* d_out, int out_size, void* d_ws, size_t ws_size,
                              hipStream_t stream) {
  const float* pts  = (const float*)d_in[0];
  const float* ew1  = (const float*)d_in[1];
  const float* eb1  = (const float*)d_in[2];
  const float* ew2  = (const float*)d_in[3];
  const float* eb2  = (const float*)d_in[4];
  const float* ew3  = (const float*)d_in[5];
  const float* eb3  = (const float*)d_in[6];
  const float* f1w1 = (const float*)d_in[7];
  const float* f1b1 = (const float*)d_in[8];
  const float* f1w2 = (const float*)d_in[9];
  const float* f1b2 = (const float*)d_in[10];
  const float* f1w3 = (const float*)d_in[11];
  const float* f1b3 = (const float*)d_in[12];
  const float* f2w1 = (const float*)d_in[13];
  const float* f2b1 = (const float*)d_in[14];
  const float* f2w2 = (const float*)d_in[15];
  const float* f2b2 = (const float*)d_in[16];
  const float* f2w3 = (const float*)d_in[17];
  const float* f2b3 = (const float*)d_in[18];
  const float* grid2= (const float*)d_in[19];

  float* out = (float*)d_out;
  unsigned* keys       = (unsigned*)d_ws;                              // 32768 B
  float* lacc          = (float*)((char*)d_ws + 32768);                // -> 33024
  float* h1b           = (float*)((char*)d_ws + 33024);                // 65536 B -> 98560
  unsigned short* w2C  = (unsigned short*)((char*)d_ws + 98560);       // 1 MB -> 1147136
  unsigned short* ew2T = (unsigned short*)((char*)d_ws + 1147136);     // 16 KB
  unsigned short* ew3T = (unsigned short*)((char*)d_ws + 1163520);     // 128 KB

  hipMemsetAsync(d_ws, 0, 98560, stream);   // keys + lacc + h1b

  tconv_kernel<<<72, 256, 0, stream>>>(ew2, ew3, ew2T, ew3T);
  w2chunk_kernel<<<256, 256, 0, stream>>>(f1w2, f2w2, w2C);
  enc2_kernel<<<512, 512, 0, stream>>>(pts, ew1, eb1, ew2T, eb2, ew3T, eb3, keys);
  decode_kernel<<<32, 256, 0, stream>>>(keys, out);                    // theta
  h1base_kernel<<<128, 256, 0, stream>>>(out, f1w1, f1b1, f2w1, f2b1, h1b);
  fold4_kernel<<<507, 512, 0, stream>>>(grid2, h1b, w2C,
                                        f1w1, f1b2, f1w3, f1b3,
                                        f2w1, f2b2, f2w3, f2b3,
                                        out + 8192);                   // pc_out
  chamA_kernel<<<512, 256, 0, stream>>>(pts, out + 8192, lacc);
  chamB_kernel<<<512, 256, 0, stream>>>(pts, out + 8192, lacc);
  fin_kernel<<<1, 64, 0, stream>>>(lacc, out + 8192 + 97200);          // loss
}

// Round 7
// 269.508 us; speedup vs baseline: 1.4893x; 1.3142x over previous
//
#include <hip/hip_runtime.h>

#define NBATCH 16
#define NPTS   2048
#define MQ     2025
#define CWDIM  512
#define NROWS  32400

typedef __attribute__((ext_vector_type(8))) short bf16x8;
typedef __attribute__((ext_vector_type(4))) float f32x4;

// ---------- helpers ----------
__device__ __forceinline__ unsigned fkey(float f) {
  unsigned u = __float_as_uint(f);
  return (u & 0x80000000u) ? ~u : (u | 0x80000000u);
}
__device__ __forceinline__ float funkey(unsigned u) {
  unsigned v = (u & 0x80000000u) ? (u ^ 0x80000000u) : ~u;
  return __uint_as_float(v);
}
__device__ __forceinline__ unsigned short f2bf(float f) {  // RNE f32->bf16
  unsigned u = __float_as_uint(f);
  u = (u + 0x7FFFu + ((u >> 16) & 1u)) >> 16;
  return (unsigned short)u;
}

// =====================================================================
// tconv: transpose+convert ew2 only (64x128 -> ew2T[col][k])
// =====================================================================
__global__ __launch_bounds__(256) void tconv_kernel(
    const float* __restrict__ ew2, unsigned short* __restrict__ ew2T)
{
  __shared__ float tile[32][33];
  const int tidx = blockIdx.x;              // 8 blocks: K=64, N=128
  const int kt = tidx >> 2, nt = tidx & 3;
  const int tx = threadIdx.x & 31, ty = threadIdx.x >> 5;
  #pragma unroll
  for (int j = 0; j < 4; ++j)
    tile[ty + 8 * j][tx] = ew2[(size_t)(kt * 32 + ty + 8 * j) * 128 + nt * 32 + tx];
  __syncthreads();
  #pragma unroll
  for (int j = 0; j < 4; ++j)
    ew2T[(size_t)(nt * 32 + ty + 8 * j) * 64 + kt * 32 + tx] = f2bf(tile[tx][ty + 8 * j]);
}

// =====================================================================
// w2chunk: fold layer-2 weights -> fragment-chunked bf16:
// chunk rem = [kt(16)][cblk(32)][hi(4)][c16(16)], elem j:
//   w2C[s][rem*8+j] = bf16(w2[kt*32 + hi*8 + j][cblk*16 + c16])
// A wave's (kt,n) B-fragment = 1 contiguous KB.
// =====================================================================
__global__ __launch_bounds__(256) void w2chunk_kernel(
    const float* __restrict__ f1w2, const float* __restrict__ f2w2,
    unsigned short* __restrict__ w2C)
{
  const int gid = blockIdx.x * 256 + threadIdx.x;   // 65536
  const int s = gid >> 15;
  const int rem = gid & 32767;
  const int c16 = rem & 15, hi = (rem >> 4) & 3, cblk = (rem >> 6) & 31, kt = rem >> 11;
  const int col = cblk * 16 + c16;
  const float* src = s ? f2w2 : f1w2;
  unsigned short tmp[8];
  #pragma unroll
  for (int j = 0; j < 8; ++j)
    tmp[j] = f2bf(src[(size_t)(kt * 32 + hi * 8 + j) * 512 + col]);
  int4 pk;
  pk.x = (int)((unsigned)tmp[0] | ((unsigned)tmp[1] << 16));
  pk.y = (int)((unsigned)tmp[2] | ((unsigned)tmp[3] << 16));
  pk.z = (int)((unsigned)tmp[4] | ((unsigned)tmp[5] << 16));
  pk.w = (int)((unsigned)tmp[6] | ((unsigned)tmp[7] << 16));
  *(int4*)&w2C[(size_t)s * 262144 + (size_t)rem * 8] = pk;
}

// =====================================================================
// ew3chunk: encoder layer-3 weights, same fragment-chunk layout
// rem = [kblk(4)][cblk(32)][hi(4)][c16(16)]; k = kblk*32+hi*8+j (<128)
// =====================================================================
__global__ __launch_bounds__(256) void ew3chunk_kernel(
    const float* __restrict__ ew3, unsigned short* __restrict__ ew3C)
{
  const int gid = blockIdx.x * 256 + threadIdx.x;   // 8192
  const int c16 = gid & 15, hi = (gid >> 4) & 3, cblk = (gid >> 6) & 31, kblk = gid >> 11;
  const int col = cblk * 16 + c16;
  unsigned short tmp[8];
  #pragma unroll
  for (int j = 0; j < 8; ++j)
    tmp[j] = f2bf(ew3[(size_t)(kblk * 32 + hi * 8 + j) * 512 + col]);
  int4 pk;
  pk.x = (int)((unsigned)tmp[0] | ((unsigned)tmp[1] << 16));
  pk.y = (int)((unsigned)tmp[2] | ((unsigned)tmp[3] << 16));
  pk.z = (int)((unsigned)tmp[4] | ((unsigned)tmp[5] << 16));
  pk.w = (int)((unsigned)tmp[6] | ((unsigned)tmp[7] << 16));
  *(int4*)&ew3C[(size_t)gid * 8] = pk;
}

// =====================================================================
// Encoder (MFMA): block = 64 points, 512 thr = 8 waves.
// layer-3 B now from chunked ew3C (lane-contiguous 1KB loads).
// =====================================================================
__global__ __launch_bounds__(512, 2) void enc2_kernel(
    const float* __restrict__ pts,
    const float* __restrict__ ew1, const float* __restrict__ eb1,
    const unsigned short* __restrict__ ew2T, const float* __restrict__ eb2,
    const unsigned short* __restrict__ ew3C, const float* __restrict__ eb3,
    unsigned* __restrict__ keys)
{
  __shared__ unsigned short h1s[64 * 64];
  __shared__ unsigned short h2s[64 * 128];
  __shared__ float s_pts[64][4];
  const int t = threadIdx.x;
  const int b = blockIdx.x >> 5, p0 = (blockIdx.x & 31) << 6;
  if (t < 64)
    *(float4*)&s_pts[t][0] = *(const float4*)(pts + ((size_t)b * NPTS + p0 + t) * 4);
  __syncthreads();

  {
    const int c = t & 63;
    const float w0 = ew1[c], w1 = ew1[64 + c], w2 = ew1[128 + c], w3 = ew1[192 + c];
    const float bb = eb1[c];
    #pragma unroll
    for (int i = 0; i < 8; ++i) {
      const int p = i * 8 + (t >> 6);
      float acc = bb + s_pts[p][0] * w0 + s_pts[p][1] * w1 + s_pts[p][2] * w2 + s_pts[p][3] * w3;
      unsigned byte = ((unsigned)p << 7) + ((unsigned)c << 1);
      byte ^= ((unsigned)(p & 7)) << 4;
      h1s[byte >> 1] = f2bf(fmaxf(acc, 0.f));
    }
  }
  __syncthreads();

  const int wv = t >> 6, lane = t & 63, l15 = lane & 15, hi = lane >> 4;

  {
    f32x4 acc[4];
    #pragma unroll
    for (int m = 0; m < 4; ++m) acc[m] = (f32x4){0.f, 0.f, 0.f, 0.f};
    const int col = 16 * wv + l15;
    #pragma unroll
    for (int kk = 0; kk < 64; kk += 32) {
      bf16x8 bv = *(const bf16x8*)(ew2T + (size_t)col * 64 + kk + hi * 8);
      #pragma unroll
      for (int m = 0; m < 4; ++m) {
        const int row = 16 * m + l15;
        unsigned byte = ((unsigned)row << 7) + ((unsigned)((kk + hi * 8)) << 1);
        byte ^= ((unsigned)(row & 7)) << 4;
        bf16x8 av = *(const bf16x8*)&h1s[byte >> 1];
        acc[m] = __builtin_amdgcn_mfma_f32_16x16x32_bf16(av, bv, acc[m], 0, 0, 0);
      }
    }
    const float b2c = eb2[col];
    #pragma unroll
    for (int m = 0; m < 4; ++m)
      #pragma unroll
      for (int r = 0; r < 4; ++r) {
        const int row = 16 * m + hi * 4 + r;
        unsigned byte = ((unsigned)row << 8) + ((unsigned)col << 1);
        byte ^= ((unsigned)(row & 7)) << 4;
        h2s[byte >> 1] = f2bf(fmaxf(acc[m][r] + b2c, 0.f));
      }
  }
  __syncthreads();

  {
    f32x4 acc[4][4];
    #pragma unroll
    for (int m = 0; m < 4; ++m)
      #pragma unroll
      for (int n = 0; n < 4; ++n) acc[m][n] = (f32x4){0.f, 0.f, 0.f, 0.f};
    #pragma unroll
    for (int kk = 0; kk < 128; kk += 32) {
      bf16x8 av[4];
      #pragma unroll
      for (int m = 0; m < 4; ++m) {
        const int row = 16 * m + l15;
        unsigned byte = ((unsigned)row << 8) + ((unsigned)(kk + hi * 8) << 1);
        byte ^= ((unsigned)(row & 7)) << 4;
        av[m] = *(const bf16x8*)&h2s[byte >> 1];
      }
      #pragma unroll
      for (int n = 0; n < 4; ++n) {
        // chunk = (kk>>5)*32 + 4*wv + n; fragment = chunk*512 + lane*8
        bf16x8 bv = *(const bf16x8*)(ew3C +
            (size_t)(((kk >> 5) * 32 + 4 * wv + n) * 512) + lane * 8);
        #pragma unroll
        for (int m = 0; m < 4; ++m)
          acc[m][n] = __builtin_amdgcn_mfma_f32_16x16x32_bf16(av[m], bv, acc[m][n], 0, 0, 0);
      }
    }
    #pragma unroll
    for (int n = 0; n < 4; ++n) {
      const int col = 64 * wv + 16 * n + l15;
      float mx = -1e30f;
      #pragma unroll
      for (int m = 0; m < 4; ++m)
        #pragma unroll
        for (int r = 0; r < 4; ++r) mx = fmaxf(mx, acc[m][n][r]);
      mx = fmaxf(mx, __shfl_xor(mx, 16));
      mx = fmaxf(mx, __shfl_xor(mx, 32));
      if (hi == 0) atomicMax(&keys[b * CWDIM + col], fkey(mx + eb3[col]));
    }
  }
}

__global__ __launch_bounds__(256) void decode_kernel(const unsigned* __restrict__ keys,
                                                     float* __restrict__ theta) {
  int i = blockIdx.x * 256 + threadIdx.x;
  theta[i] = funkey(keys[i]);
}

// =====================================================================
// h1base split-K x2: atomicAdd partials (h1b pre-zeroed by memset)
// =====================================================================
__global__ __launch_bounds__(256) void h1base_kernel(
    const float* __restrict__ theta,
    const float* __restrict__ f1w1, const float* __restrict__ f1b1,
    const float* __restrict__ f2w1, const float* __restrict__ f2b1,
    float* __restrict__ h1b)
{
  int gid = blockIdx.x * 256 + threadIdx.x;   // 32768
  int half = gid >> 14;
  int rem = gid & 16383;
  int stage = rem >> 13, bb = (rem >> 9) & 15, c = rem & 511;
  const float* w = stage ? f2w1 : f1w1;
  float acc = 0.f;
  if (half == 0) acc = stage ? f2b1[c] : f1b1[c];
  const float* th = theta + bb * 512 + half * 256;
  const float* wp = w + (size_t)(half * 256) * 512 + c;
  #pragma unroll 8
  for (int k = 0; k < 256; ++k) acc += th[k] * wp[(size_t)k * 512];
  atomicAdd(&h1b[rem], acc);
}

// =====================================================================
// fold5: BM=64 (507 blocks), 8 waves = 2M x 4N, N=512 in 2 passes of 256.
// A in LDS (fragment-contiguous layout, built once per stage, 1 barrier).
// B streamed per-wave into REGISTERS from chunked w2C (1KB contiguous
// loads) -> ZERO barriers in the K-loop. ~70KB LDS -> 2 blocks/CU.
// =====================================================================
struct Fold5Smem {
  unsigned short sA[64 * 512];   // 64 KB: idx = (kt*4+g)*512 + hi*128 + l15*8
  float red[8][32][3];           // 3 KB
  float ext[64][4];              // 1 KB
  int   rowbb[64];               // 256 B
};

template <int ST>
__device__ __forceinline__ void fold5_stage(Fold5Smem& S, int t, int r0,
    const float* __restrict__ h1bg,
    const float* __restrict__ w1,
    const unsigned short* __restrict__ wst,   // chunked [kt][cblk][hi][c16][8]
    const float* __restrict__ b2, const float* __restrict__ w3,
    const float* __restrict__ b3, float* __restrict__ out_pc)
{
  constexpr int NE = ST ? 3 : 2;
  const int wv = t >> 6, lane = t & 63, l15 = lane & 15, hi = lane >> 4;
  const int wm = wv >> 2, wn = wv & 3;

  __syncthreads();   // ext (grid init or prev-stage epilogue) ready

  // ---- A-build: 64x512 tile -> sA (fragment-contiguous), once per stage
  {
    const int row = t & 63;
    const int bb = S.rowbb[row];
    const float e0 = S.ext[row][0], e1 = S.ext[row][1];
    float e2 = 0.f;
    if (NE == 3) e2 = S.ext[row][2];
    const float* hb  = h1bg + ST * 8192 + bb * 512;
    const float* wr0 = w1 + (size_t)512 * 512;
    const float* wr1 = wr0 + 512;
    const float* wr2 = wr1 + 512;
    #pragma unroll
    for (int i = 0; i < 8; ++i) {
      const int ko = (t >> 6) * 8 + i;      // K-octet 0..63 (wave-uniform)
      const int c0 = ko * 8;
      float v[8];
      #pragma unroll
      for (int hf = 0; hf < 2; ++hf) {
        float4 h = *(const float4*)(hb + c0 + hf * 4);
        float4 a = *(const float4*)(wr0 + c0 + hf * 4);
        float4 bq = *(const float4*)(wr1 + c0 + hf * 4);
        v[hf * 4 + 0] = h.x + e0 * a.x + e1 * bq.x;
        v[hf * 4 + 1] = h.y + e0 * a.y + e1 * bq.y;
        v[hf * 4 + 2] = h.z + e0 * a.z + e1 * bq.z;
        v[hf * 4 + 3] = h.w + e0 * a.w + e1 * bq.w;
        if (NE == 3) {
          float4 cq = *(const float4*)(wr2 + c0 + hf * 4);
          v[hf * 4 + 0] += e2 * cq.x; v[hf * 4 + 1] += e2 * cq.y;
          v[hf * 4 + 2] += e2 * cq.z; v[hf * 4 + 3] += e2 * cq.w;
        }
      }
      int4 pk;
      pk.x = (int)((unsigned)f2bf(fmaxf(v[0], 0.f)) | ((unsigned)f2bf(fmaxf(v[1], 0.f)) << 16));
      pk.y = (int)((unsigned)f2bf(fmaxf(v[2], 0.f)) | ((unsigned)f2bf(fmaxf(v[3], 0.f)) << 16));
      pk.z = (int)((unsigned)f2bf(fmaxf(v[4], 0.f)) | ((unsigned)f2bf(fmaxf(v[5], 0.f)) << 16));
      pk.w = (int)((unsigned)f2bf(fmaxf(v[6], 0.f)) | ((unsigned)f2bf(fmaxf(v[7], 0.f)) << 16));
      // idx = ((ko>>2)*4 + row>>4)*512 + (ko&3)*128 + (row&15)*8
      *(int4*)&S.sA[(unsigned)(((ko >> 2) * 4 + (row >> 4)) * 512 + (ko & 3) * 128 + (row & 15) * 8)] = pk;
    }
  }
  __syncthreads();

  float p[2][4][3];
  #pragma unroll
  for (int m = 0; m < 2; ++m)
    #pragma unroll
    for (int r = 0; r < 4; ++r)
      #pragma unroll
      for (int jj = 0; jj < 3; ++jj) p[m][r][jj] = 0.f;

  #pragma unroll 1
  for (int pass = 0; pass < 2; ++pass) {
    f32x4 acc[2][4];
    #pragma unroll
    for (int m = 0; m < 2; ++m)
      #pragma unroll
      for (int n = 0; n < 4; ++n) acc[m][n] = (f32x4){0.f, 0.f, 0.f, 0.f};

    // per-wave B base: chunk (kt*32 + pass*16 + wn*4 + n), lane-contiguous
    const unsigned short* wb = wst + (size_t)(pass * 16 + wn * 4) * 512 + lane * 8;

    #pragma unroll 2
    for (int kt = 0; kt < 16; ++kt) {
      bf16x8 bv[4];
      #pragma unroll
      for (int n = 0; n < 4; ++n)
        bv[n] = *(const bf16x8*)(wb + (size_t)(kt * 32 + n) * 512);
      const unsigned abase = (unsigned)(kt * 4 + 2 * wm) * 512 + (unsigned)lane * 8;
      bf16x8 a0 = *(const bf16x8*)&S.sA[abase];
      bf16x8 a1 = *(const bf16x8*)&S.sA[abase + 512];
      #pragma unroll
      for (int n = 0; n < 4; ++n) {
        acc[0][n] = __builtin_amdgcn_mfma_f32_16x16x32_bf16(a0, bv[n], acc[0][n], 0, 0, 0);
        acc[1][n] = __builtin_amdgcn_mfma_f32_16x16x32_bf16(a1, bv[n], acc[1][n], 0, 0, 0);
      }
    }

    // layer-3 partials (b2/w3 from L2 — small, broadcast-cached)
    #pragma unroll
    for (int n = 0; n < 4; ++n) {
      const int colG = pass * 256 + wn * 64 + 16 * n + l15;
      const float b2c = b2[colG];
      const float w30 = w3[colG * 3 + 0], w31 = w3[colG * 3 + 1], w32 = w3[colG * 3 + 2];
      #pragma unroll
      for (int m = 0; m < 2; ++m)
        #pragma unroll
        for (int r = 0; r < 4; ++r) {
          const float h = fmaxf(acc[m][n][r] + b2c, 0.f);
          p[m][r][0] += h * w30; p[m][r][1] += h * w31; p[m][r][2] += h * w32;
        }
    }
  }

  // reduce p over the 16 col-lanes
  #pragma unroll
  for (int m = 0; m < 2; ++m)
    #pragma unroll
    for (int r = 0; r < 4; ++r)
      #pragma unroll
      for (int jj = 0; jj < 3; ++jj) {
        float v = p[m][r][jj];
        v += __shfl_xor(v, 1); v += __shfl_xor(v, 2);
        v += __shfl_xor(v, 4); v += __shfl_xor(v, 8);
        p[m][r][jj] = v;
      }
  if (l15 == 0) {
    #pragma unroll
    for (int m = 0; m < 2; ++m)
      #pragma unroll
      for (int r = 0; r < 4; ++r) {
        const int rl = 16 * m + hi * 4 + r;
        S.red[wv][rl][0] = p[m][r][0];
        S.red[wv][rl][1] = p[m][r][1];
        S.red[wv][rl][2] = p[m][r][2];
      }
  }
  __syncthreads();

  if (t < 192) {
    const int row = t / 3, jj = t - (t / 3) * 3;
    const int wg = (row >> 5) * 4, rl = row & 31;
    float v = b3[jj] + S.red[wg][rl][jj] + S.red[wg + 1][rl][jj]
                     + S.red[wg + 2][rl][jj] + S.red[wg + 3][rl][jj];
    if (ST == 0) S.ext[row][jj] = v;
    else if (r0 + row < NROWS) out_pc[(size_t)(r0 + row) * 3 + jj] = v;
  }
  __syncthreads();
}

__global__ __launch_bounds__(512, 2) void fold5_kernel(
    const float* __restrict__ grid2, const float* __restrict__ h1b,
    const unsigned short* __restrict__ w2C,
    const float* __restrict__ f1w1, const float* __restrict__ f1b2,
    const float* __restrict__ f1w3, const float* __restrict__ f1b3,
    const float* __restrict__ f2w1, const float* __restrict__ f2b2,
    const float* __restrict__ f2w3, const float* __restrict__ f2b3,
    float* __restrict__ out_pc)
{
  __shared__ Fold5Smem S;
  const int t = threadIdx.x;
  const int r0 = blockIdx.x * 64;

  if (t < 64) {
    const int r = r0 + t;
    const int bb = min(r / MQ, NBATCH - 1);
    S.rowbb[t] = bb;
    const int m = min(r - bb * MQ, MQ - 1);
    S.ext[t][0] = grid2[m * 2 + 0];
    S.ext[t][1] = grid2[m * 2 + 1];
    S.ext[t][2] = 0.f;
    S.ext[t][3] = 0.f;
  }
  // stage-entry barrier inside fold5_stage orders these writes

  fold5_stage<0>(S, t, r0, h1b, f1w1, w2C,          f1b2, f1w3, f1b3, nullptr);
  fold5_stage<1>(S, t, r0, h1b, f2w1, w2C + 262144, f2b2, f2w3, f2b3, out_pc);
}

// =====================================================================
// Chamfer A / B (unchanged, passed)
// =====================================================================
__global__ __launch_bounds__(256) void chamA_kernel(const float* __restrict__ pts,
                                                    const float* __restrict__ pc,
                                                    float* __restrict__ lacc)
{
  __shared__ float sbx[2048], sby[2048], sbz[2048];
  const int t = threadIdx.x;
  const int b = blockIdx.x >> 5;
  const int n0 = (blockIdx.x & 31) << 6;
  const float* pcb = pc + (size_t)b * (MQ * 3);
  for (int i = t; i < MQ * 3; i += 256) {
    float v = pcb[i];
    int m = i / 3, j = i - m * 3;
    if (j == 0) sbx[m] = v; else if (j == 1) sby[m] = v; else sbz[m] = v;
  }
  for (int i = MQ + t; i < 2048; i += 256) { sbx[i] = 1e30f; sby[i] = 1e30f; sbz[i] = 1e30f; }
  __syncthreads();

  const int pid = t >> 4, q = t & 15;
  float ax[4], ay[4], az[4], mn[4];
  #pragma unroll
  for (int j = 0; j < 4; ++j) {
    const int n = n0 + pid * 4 + j;
    float4 P = *(const float4*)(pts + ((size_t)b * NPTS + n) * 4);
    ax[j] = P.x; ay[j] = P.y; az[j] = P.z + P.w; mn[j] = 1e30f;
  }
  #pragma unroll 4
  for (int i = 0; i < 32; ++i) {
    const int m4 = q * 4 + i * 64;
    float4 bx = *(const float4*)&sbx[m4];
    float4 by = *(const float4*)&sby[m4];
    float4 bz = *(const float4*)&sbz[m4];
    #pragma unroll
    for (int j = 0; j < 4; ++j) {
      float d0, dx, dy, dz;
      dx = ax[j] - bx.x; dy = ay[j] - by.x; dz = az[j] - bz.x; d0 = dx*dx + dy*dy + dz*dz; mn[j] = fminf(mn[j], d0);
      dx = ax[j] - bx.y; dy = ay[j] - by.y; dz = az[j] - bz.y; d0 = dx*dx + dy*dy + dz*dz; mn[j] = fminf(mn[j], d0);
      dx = ax[j] - bx.z; dy = ay[j] - by.z; dz = az[j] - bz.z; d0 = dx*dx + dy*dy + dz*dz; mn[j] = fminf(mn[j], d0);
      dx = ax[j] - bx.w; dy = ay[j] - by.w; dz = az[j] - bz.w; d0 = dx*dx + dy*dy + dz*dz; mn[j] = fminf(mn[j], d0);
    }
  }
  #pragma unroll
  for (int j = 0; j < 4; ++j) {
    mn[j] = fminf(mn[j], __shfl_xor(mn[j], 1));
    mn[j] = fminf(mn[j], __shfl_xor(mn[j], 2));
    mn[j] = fminf(mn[j], __shfl_xor(mn[j], 4));
    mn[j] = fminf(mn[j], __shfl_xor(mn[j], 8));
  }
  float v = (q == 0) ? (mn[0] + mn[1] + mn[2] + mn[3]) : 0.f;
  v += __shfl_xor(v, 16); v += __shfl_xor(v, 32);
  if ((t & 63) == 0) atomicAdd(lacc, v);
}

__global__ __launch_bounds__(256) void chamB_kernel(const float* __restrict__ pts,
                                                    const float* __restrict__ pc,
                                                    float* __restrict__ lacc)
{
  __shared__ float sax[2048], say[2048], saz[2048];
  const int t = threadIdx.x;
  const int b = blockIdx.x >> 5;
  const int m0 = (blockIdx.x & 31) << 6;
  for (int i = t; i < NPTS; i += 256) {
    float4 pp = *(const float4*)(pts + ((size_t)b * NPTS + i) * 4);
    sax[i] = pp.x; say[i] = pp.y; saz[i] = pp.z + pp.w;
  }
  __syncthreads();

  const int pid = t >> 4, q = t & 15;
  float bx[4], by[4], bz[4], mn[4];
  bool vld[4];
  #pragma unroll
  for (int j = 0; j < 4; ++j) {
    const int m = m0 + pid * 4 + j;
    vld[j] = (m < MQ);
    const int mc = vld[j] ? m : (MQ - 1);
    bx[j] = pc[(size_t)b * (MQ * 3) + mc * 3 + 0];
    by[j] = pc[(size_t)b * (MQ * 3) + mc * 3 + 1];
    bz[j] = pc[(size_t)b * (MQ * 3) + mc * 3 + 2];
    mn[j] = 1e30f;
  }
  #pragma unroll 4
  for (int i = 0; i < 32; ++i) {
    const int n4 = q * 4 + i * 64;
    float4 axv = *(const float4*)&sax[n4];
    float4 ayv = *(const float4*)&say[n4];
    float4 azv = *(const float4*)&saz[n4];
    #pragma unroll
    for (int j = 0; j < 4; ++j) {
      float d0, dx, dy, dz;
      dx = axv.x - bx[j]; dy = ayv.x - by[j]; dz = azv.x - bz[j]; d0 = dx*dx + dy*dy + dz*dz; mn[j] = fminf(mn[j], d0);
      dx = axv.y - bx[j]; dy = ayv.y - by[j]; dz = azv.y - bz[j]; d0 = dx*dx + dy*dy + dz*dz; mn[j] = fminf(mn[j], d0);
      dx = axv.z - bx[j]; dy = ayv.z - by[j]; dz = azv.z - bz[j]; d0 = dx*dx + dy*dy + dz*dz; mn[j] = fminf(mn[j], d0);
      dx = axv.w - bx[j]; dy = ayv.w - by[j]; dz = azv.w - bz[j]; d0 = dx*dx + dy*dy + dz*dz; mn[j] = fminf(mn[j], d0);
    }
  }
  #pragma unroll
  for (int j = 0; j < 4; ++j) {
    mn[j] = fminf(mn[j], __shfl_xor(mn[j], 1));
    mn[j] = fminf(mn[j], __shfl_xor(mn[j], 2));
    mn[j] = fminf(mn[j], __shfl_xor(mn[j], 4));
    mn[j] = fminf(mn[j], __shfl_xor(mn[j], 8));
  }
  float v = 0.f;
  if (q == 0) {
    #pragma unroll
    for (int j = 0; j < 4; ++j) if (vld[j]) v += mn[j];
  }
  v += __shfl_xor(v, 16); v += __shfl_xor(v, 32);
  if ((t & 63) == 0) atomicAdd(lacc + 1, v);
}

__global__ void fin_kernel(const float* __restrict__ lacc, float* __restrict__ loss) {
  if (threadIdx.x == 0 && blockIdx.x == 0)
    loss[0] = lacc[0] * (1.0f / (NBATCH * NPTS)) + lacc[1] * (1.0f / (NBATCH * MQ));
}

// =====================================================================
extern "C" void kernel_launch(void* const* d_in, const int* in_sizes, int n_in,
                              void* d_out, int out_size, void* d_ws, size_t ws_size,
                              hipStream_t stream) {
  const float* pts  = (const float*)d_in[0];
  const float* ew1  = (const float*)d_in[1];
  const float* eb1  = (const float*)d_in[2];
  const float* ew2  = (const float*)d_in[3];
  const float* eb2  = (const float*)d_in[4];
  const float* ew3  = (const float*)d_in[5];
  const float* eb3  = (const float*)d_in[6];
  const float* f1w1 = (const float*)d_in[7];
  const float* f1b1 = (const float*)d_in[8];
  const float* f1w2 = (const float*)d_in[9];
  const float* f1b2 = (const float*)d_in[10];
  const float* f1w3 = (const float*)d_in[11];
  const float* f1b3 = (const float*)d_in[12];
  const float* f2w1 = (const float*)d_in[13];
  const float* f2b1 = (const float*)d_in[14];
  const float* f2w2 = (const float*)d_in[15];
  const float* f2b2 = (const float*)d_in[16];
  const float* f2w3 = (const float*)d_in[17];
  const float* f2b3 = (const float*)d_in[18];
  const float* grid2= (const float*)d_in[19];

  float* out = (float*)d_out;
  unsigned* keys       = (unsigned*)d_ws;                              // 32768 B
  float* lacc          = (float*)((char*)d_ws + 32768);                // -> 33024
  float* h1b           = (float*)((char*)d_ws + 33024);                // 65536 B -> 98560
  unsigned short* w2C  = (unsigned short*)((char*)d_ws + 98560);       // 1 MB -> 1147136
  unsigned short* ew2T = (unsigned short*)((char*)d_ws + 1147136);     // 16 KB
  unsigned short* ew3C = (unsigned short*)((char*)d_ws + 1163520);     // 128 KB

  hipMemsetAsync(d_ws, 0, 98560, stream);   // keys + lacc + h1b

  tconv_kernel<<<8, 256, 0, stream>>>(ew2, ew2T);
  w2chunk_kernel<<<256, 256, 0, stream>>>(f1w2, f2w2, w2C);
  ew3chunk_kernel<<<32, 256, 0, stream>>>(ew3, ew3C);
  enc2_kernel<<<512, 512, 0, stream>>>(pts, ew1, eb1, ew2T, eb2, ew3C, eb3, keys);
  decode_kernel<<<32, 256, 0, stream>>>(keys, out);                    // theta
  h1base_kernel<<<128, 256, 0, stream>>>(out, f1w1, f1b1, f2w1, f2b1, h1b);
  fold5_kernel<<<507, 512, 0, stream>>>(grid2, h1b, w2C,
                                        f1w1, f1b2, f1w3, f1b3,
                                        f2w1, f2b2, f2w3, f2b3,
                                        out + 8192);                   // pc_out
  chamA_kernel<<<512, 256, 0, stream>>>(pts, out + 8192, lacc);
  chamB_kernel<<<512, 256, 0, stream>>>(pts, out + 8192, lacc);
  fin_kernel<<<1, 64, 0, stream>>>(lacc, out + 8192 + 97200);          // loss
}

// Round 8
// 253.436 us; speedup vs baseline: 1.5837x; 1.0634x over previous
//
#include <hip/hip_runtime.h>

#define NBATCH 16
#define NPTS   2048
#define MQ     2025
#define CWDIM  512
#define NROWS  32400

typedef __attribute__((ext_vector_type(8))) short bf16x8;
typedef __attribute__((ext_vector_type(4))) float f32x4;

// ---------- helpers ----------
__device__ __forceinline__ unsigned fkey(float f) {
  unsigned u = __float_as_uint(f);
  return (u & 0x80000000u) ? ~u : (u | 0x80000000u);
}
__device__ __forceinline__ float funkey(unsigned u) {
  unsigned v = (u & 0x80000000u) ? (u ^ 0x80000000u) : ~u;
  return __uint_as_float(v);
}
__device__ __forceinline__ unsigned short f2bf(float f) {  // RNE f32->bf16
  unsigned u = __float_as_uint(f);
  u = (u + 0x7FFFu + ((u >> 16) & 1u)) >> 16;
  return (unsigned short)u;
}

// =====================================================================
// prep: fused weight-prep + workspace zeroing (replaces tconv, w2chunk,
// ew3chunk, hipMemsetAsync -> 1 dispatch instead of 4)
// blocks: [0,8) ew2 transpose | [8,40) ew3chunk | [40,296) w2chunk |
//         [296,320) zero keys/lacc/h1b
// =====================================================================
__global__ __launch_bounds__(256) void prep_kernel(
    const float* __restrict__ ew2, const float* __restrict__ ew3,
    const float* __restrict__ f1w2, const float* __restrict__ f2w2,
    unsigned short* __restrict__ ew2T, unsigned short* __restrict__ ew3C,
    unsigned short* __restrict__ w2C, unsigned* __restrict__ zws)
{
  __shared__ float tile[32][33];
  const int blk = blockIdx.x;
  const int t = threadIdx.x;

  if (blk < 8) {                     // ---- ew2 (64x128) -> ew2T[col][k]
    const int kt = blk >> 2, nt = blk & 3;
    const int tx = t & 31, ty = t >> 5;
    #pragma unroll
    for (int j = 0; j < 4; ++j)
      tile[ty + 8 * j][tx] = ew2[(size_t)(kt * 32 + ty + 8 * j) * 128 + nt * 32 + tx];
    __syncthreads();
    #pragma unroll
    for (int j = 0; j < 4; ++j)
      ew2T[(size_t)(nt * 32 + ty + 8 * j) * 64 + kt * 32 + tx] = f2bf(tile[tx][ty + 8 * j]);
  } else if (blk < 40) {             // ---- ew3 fragment-chunk (8192 chunks-of-8)
    const int gid = (blk - 8) * 256 + t;
    const int c16 = gid & 15, hi = (gid >> 4) & 3, cblk = (gid >> 6) & 31, kblk = gid >> 11;
    const int col = cblk * 16 + c16;
    unsigned short tmp[8];
    #pragma unroll
    for (int j = 0; j < 8; ++j)
      tmp[j] = f2bf(ew3[(size_t)(kblk * 32 + hi * 8 + j) * 512 + col]);
    int4 pk;
    pk.x = (int)((unsigned)tmp[0] | ((unsigned)tmp[1] << 16));
    pk.y = (int)((unsigned)tmp[2] | ((unsigned)tmp[3] << 16));
    pk.z = (int)((unsigned)tmp[4] | ((unsigned)tmp[5] << 16));
    pk.w = (int)((unsigned)tmp[6] | ((unsigned)tmp[7] << 16));
    *(int4*)&ew3C[(size_t)gid * 8] = pk;
  } else if (blk < 296) {            // ---- w2 fragment-chunk (2 stages)
    const int gid = (blk - 40) * 256 + t;       // 65536
    const int s = gid >> 15;
    const int rem = gid & 32767;
    const int c16 = rem & 15, hi = (rem >> 4) & 3, cblk = (rem >> 6) & 31, kt = rem >> 11;
    const int col = cblk * 16 + c16;
    const float* src = s ? f2w2 : f1w2;
    unsigned short tmp[8];
    #pragma unroll
    for (int j = 0; j < 8; ++j)
      tmp[j] = f2bf(src[(size_t)(kt * 32 + hi * 8 + j) * 512 + col]);
    int4 pk;
    pk.x = (int)((unsigned)tmp[0] | ((unsigned)tmp[1] << 16));
    pk.y = (int)((unsigned)tmp[2] | ((unsigned)tmp[3] << 16));
    pk.z = (int)((unsigned)tmp[4] | ((unsigned)tmp[5] << 16));
    pk.w = (int)((unsigned)tmp[6] | ((unsigned)tmp[7] << 16));
    *(int4*)&w2C[(size_t)s * 262144 + (size_t)rem * 8] = pk;
  } else {                           // ---- zero keys(32768B)+lacc(256B)+h1b(64KB)
    const int idx = (blk - 296) * 256 + t;      // 6144 threads
    for (int i = idx; i < 24640; i += 6144) zws[i] = 0u;
  }
}

// =====================================================================
// Encoder (MFMA): block = 64 points, 512 thr = 8 waves. (unchanged, passed)
// =====================================================================
__global__ __launch_bounds__(512, 2) void enc2_kernel(
    const float* __restrict__ pts,
    const float* __restrict__ ew1, const float* __restrict__ eb1,
    const unsigned short* __restrict__ ew2T, const float* __restrict__ eb2,
    const unsigned short* __restrict__ ew3C, const float* __restrict__ eb3,
    unsigned* __restrict__ keys)
{
  __shared__ unsigned short h1s[64 * 64];
  __shared__ unsigned short h2s[64 * 128];
  __shared__ float s_pts[64][4];
  const int t = threadIdx.x;
  const int b = blockIdx.x >> 5, p0 = (blockIdx.x & 31) << 6;
  if (t < 64)
    *(float4*)&s_pts[t][0] = *(const float4*)(pts + ((size_t)b * NPTS + p0 + t) * 4);
  __syncthreads();

  {
    const int c = t & 63;
    const float w0 = ew1[c], w1 = ew1[64 + c], w2 = ew1[128 + c], w3 = ew1[192 + c];
    const float bb = eb1[c];
    #pragma unroll
    for (int i = 0; i < 8; ++i) {
      const int p = i * 8 + (t >> 6);
      float acc = bb + s_pts[p][0] * w0 + s_pts[p][1] * w1 + s_pts[p][2] * w2 + s_pts[p][3] * w3;
      unsigned byte = ((unsigned)p << 7) + ((unsigned)c << 1);
      byte ^= ((unsigned)(p & 7)) << 4;
      h1s[byte >> 1] = f2bf(fmaxf(acc, 0.f));
    }
  }
  __syncthreads();

  const int wv = t >> 6, lane = t & 63, l15 = lane & 15, hi = lane >> 4;

  {
    f32x4 acc[4];
    #pragma unroll
    for (int m = 0; m < 4; ++m) acc[m] = (f32x4){0.f, 0.f, 0.f, 0.f};
    const int col = 16 * wv + l15;
    #pragma unroll
    for (int kk = 0; kk < 64; kk += 32) {
      bf16x8 bv = *(const bf16x8*)(ew2T + (size_t)col * 64 + kk + hi * 8);
      #pragma unroll
      for (int m = 0; m < 4; ++m) {
        const int row = 16 * m + l15;
        unsigned byte = ((unsigned)row << 7) + ((unsigned)((kk + hi * 8)) << 1);
        byte ^= ((unsigned)(row & 7)) << 4;
        bf16x8 av = *(const bf16x8*)&h1s[byte >> 1];
        acc[m] = __builtin_amdgcn_mfma_f32_16x16x32_bf16(av, bv, acc[m], 0, 0, 0);
      }
    }
    const float b2c = eb2[col];
    #pragma unroll
    for (int m = 0; m < 4; ++m)
      #pragma unroll
      for (int r = 0; r < 4; ++r) {
        const int row = 16 * m + hi * 4 + r;
        unsigned byte = ((unsigned)row << 8) + ((unsigned)col << 1);
        byte ^= ((unsigned)(row & 7)) << 4;
        h2s[byte >> 1] = f2bf(fmaxf(acc[m][r] + b2c, 0.f));
      }
  }
  __syncthreads();

  {
    f32x4 acc[4][4];
    #pragma unroll
    for (int m = 0; m < 4; ++m)
      #pragma unroll
      for (int n = 0; n < 4; ++n) acc[m][n] = (f32x4){0.f, 0.f, 0.f, 0.f};
    #pragma unroll
    for (int kk = 0; kk < 128; kk += 32) {
      bf16x8 av[4];
      #pragma unroll
      for (int m = 0; m < 4; ++m) {
        const int row = 16 * m + l15;
        unsigned byte = ((unsigned)row << 8) + ((unsigned)(kk + hi * 8) << 1);
        byte ^= ((unsigned)(row & 7)) << 4;
        av[m] = *(const bf16x8*)&h2s[byte >> 1];
      }
      #pragma unroll
      for (int n = 0; n < 4; ++n) {
        bf16x8 bv = *(const bf16x8*)(ew3C +
            (size_t)(((kk >> 5) * 32 + 4 * wv + n) * 512) + lane * 8);
        #pragma unroll
        for (int m = 0; m < 4; ++m)
          acc[m][n] = __builtin_amdgcn_mfma_f32_16x16x32_bf16(av[m], bv, acc[m][n], 0, 0, 0);
      }
    }
    #pragma unroll
    for (int n = 0; n < 4; ++n) {
      const int col = 64 * wv + 16 * n + l15;
      float mx = -1e30f;
      #pragma unroll
      for (int m = 0; m < 4; ++m)
        #pragma unroll
        for (int r = 0; r < 4; ++r) mx = fmaxf(mx, acc[m][n][r]);
      mx = fmaxf(mx, __shfl_xor(mx, 16));
      mx = fmaxf(mx, __shfl_xor(mx, 32));
      if (hi == 0) atomicMax(&keys[b * CWDIM + col], fkey(mx + eb3[col]));
    }
  }
}

// =====================================================================
// h1base (+ fused theta decode): split-K x2, atomicAdd partials.
// Block covers fixed (half, stage, b, c-half); theta k-slice via LDS.
// Stage-0/half-0 blocks (gid<8192) also write theta to d_out.
// =====================================================================
__global__ __launch_bounds__(256) void h1base_kernel(
    const unsigned* __restrict__ keys, float* __restrict__ theta_out,
    const float* __restrict__ f1w1, const float* __restrict__ f1b1,
    const float* __restrict__ f2w1, const float* __restrict__ f2b1,
    float* __restrict__ h1b)
{
  __shared__ float thl[256];
  const int t = threadIdx.x;
  const int gid = blockIdx.x * 256 + t;   // 32768
  const int half = gid >> 14;
  const int rem = gid & 16383;
  const int stage = rem >> 13, bb = (rem >> 9) & 15, c = rem & 511;
  thl[t] = funkey(keys[bb * 512 + half * 256 + t]);
  if (gid < 8192) theta_out[gid] = funkey(keys[gid]);
  __syncthreads();
  const float* w = stage ? f2w1 : f1w1;
  float acc = (half == 0) ? (stage ? f2b1[c] : f1b1[c]) : 0.f;
  const float* wp = w + (size_t)(half * 256) * 512 + c;
  #pragma unroll 8
  for (int k = 0; k < 256; ++k) acc += thl[k] * wp[(size_t)k * 512];
  atomicAdd(&h1b[rem], acc);
}

// =====================================================================
// fold5: BM=64 (507 blocks), 8 waves = 2M x 4N, N=512 in 2 passes of 256.
// A in LDS (built once/stage); B streamed per-wave to registers from
// chunked w2C (1KB contiguous loads) -> zero K-loop barriers.
// + s_setprio around MFMA cluster (waves are phase-diverse here).
// =====================================================================
struct Fold5Smem {
  unsigned short sA[64 * 512];   // 64 KB
  float red[8][32][3];           // 3 KB
  float ext[64][4];              // 1 KB
  int   rowbb[64];               // 256 B
};

template <int ST>
__device__ __forceinline__ void fold5_stage(Fold5Smem& S, int t, int r0,
    const float* __restrict__ h1bg,
    const float* __restrict__ w1,
    const unsigned short* __restrict__ wst,
    const float* __restrict__ b2, const float* __restrict__ w3,
    const float* __restrict__ b3, float* __restrict__ out_pc)
{
  constexpr int NE = ST ? 3 : 2;
  const int wv = t >> 6, lane = t & 63, l15 = lane & 15, hi = lane >> 4;
  const int wm = wv >> 2, wn = wv & 3;

  __syncthreads();   // ext (grid init or prev-stage epilogue) ready

  // ---- A-build: 64x512 tile -> sA (fragment-contiguous), once per stage
  {
    const int row = t & 63;
    const int bb = S.rowbb[row];
    const float e0 = S.ext[row][0], e1 = S.ext[row][1];
    float e2 = 0.f;
    if (NE == 3) e2 = S.ext[row][2];
    const float* hb  = h1bg + ST * 8192 + bb * 512;
    const float* wr0 = w1 + (size_t)512 * 512;
    const float* wr1 = wr0 + 512;
    const float* wr2 = wr1 + 512;
    #pragma unroll
    for (int i = 0; i < 8; ++i) {
      const int ko = (t >> 6) * 8 + i;
      const int c0 = ko * 8;
      float v[8];
      #pragma unroll
      for (int hf = 0; hf < 2; ++hf) {
        float4 h = *(const float4*)(hb + c0 + hf * 4);
        float4 a = *(const float4*)(wr0 + c0 + hf * 4);
        float4 bq = *(const float4*)(wr1 + c0 + hf * 4);
        v[hf * 4 + 0] = h.x + e0 * a.x + e1 * bq.x;
        v[hf * 4 + 1] = h.y + e0 * a.y + e1 * bq.y;
        v[hf * 4 + 2] = h.z + e0 * a.z + e1 * bq.z;
        v[hf * 4 + 3] = h.w + e0 * a.w + e1 * bq.w;
        if (NE == 3) {
          float4 cq = *(const float4*)(wr2 + c0 + hf * 4);
          v[hf * 4 + 0] += e2 * cq.x; v[hf * 4 + 1] += e2 * cq.y;
          v[hf * 4 + 2] += e2 * cq.z; v[hf * 4 + 3] += e2 * cq.w;
        }
      }
      int4 pk;
      pk.x = (int)((unsigned)f2bf(fmaxf(v[0], 0.f)) | ((unsigned)f2bf(fmaxf(v[1], 0.f)) << 16));
      pk.y = (int)((unsigned)f2bf(fmaxf(v[2], 0.f)) | ((unsigned)f2bf(fmaxf(v[3], 0.f)) << 16));
      pk.z = (int)((unsigned)f2bf(fmaxf(v[4], 0.f)) | ((unsigned)f2bf(fmaxf(v[5], 0.f)) << 16));
      pk.w = (int)((unsigned)f2bf(fmaxf(v[6], 0.f)) | ((unsigned)f2bf(fmaxf(v[7], 0.f)) << 16));
      *(int4*)&S.sA[(unsigned)(((ko >> 2) * 4 + (row >> 4)) * 512 + (ko & 3) * 128 + (row & 15) * 8)] = pk;
    }
  }
  __syncthreads();

  float p[2][4][3];
  #pragma unroll
  for (int m = 0; m < 2; ++m)
    #pragma unroll
    for (int r = 0; r < 4; ++r)
      #pragma unroll
      for (int jj = 0; jj < 3; ++jj) p[m][r][jj] = 0.f;

  #pragma unroll 1
  for (int pass = 0; pass < 2; ++pass) {
    f32x4 acc[2][4];
    #pragma unroll
    for (int m = 0; m < 2; ++m)
      #pragma unroll
      for (int n = 0; n < 4; ++n) acc[m][n] = (f32x4){0.f, 0.f, 0.f, 0.f};

    const unsigned short* wb = wst + (size_t)(pass * 16 + wn * 4) * 512 + lane * 8;

    #pragma unroll 2
    for (int kt = 0; kt < 16; ++kt) {
      bf16x8 bv[4];
      #pragma unroll
      for (int n = 0; n < 4; ++n)
        bv[n] = *(const bf16x8*)(wb + (size_t)(kt * 32 + n) * 512);
      const unsigned abase = (unsigned)(kt * 4 + 2 * wm) * 512 + (unsigned)lane * 8;
      bf16x8 a0 = *(const bf16x8*)&S.sA[abase];
      bf16x8 a1 = *(const bf16x8*)&S.sA[abase + 512];
      __builtin_amdgcn_s_setprio(1);
      #pragma unroll
      for (int n = 0; n < 4; ++n) {
        acc[0][n] = __builtin_amdgcn_mfma_f32_16x16x32_bf16(a0, bv[n], acc[0][n], 0, 0, 0);
        acc[1][n] = __builtin_amdgcn_mfma_f32_16x16x32_bf16(a1, bv[n], acc[1][n], 0, 0, 0);
      }
      __builtin_amdgcn_s_setprio(0);
    }

    #pragma unroll
    for (int n = 0; n < 4; ++n) {
      const int colG = pass * 256 + wn * 64 + 16 * n + l15;
      const float b2c = b2[colG];
      const float w30 = w3[colG * 3 + 0], w31 = w3[colG * 3 + 1], w32 = w3[colG * 3 + 2];
      #pragma unroll
      for (int m = 0; m < 2; ++m)
        #pragma unroll
        for (int r = 0; r < 4; ++r) {
          const float h = fmaxf(acc[m][n][r] + b2c, 0.f);
          p[m][r][0] += h * w30; p[m][r][1] += h * w31; p[m][r][2] += h * w32;
        }
    }
  }

  #pragma unroll
  for (int m = 0; m < 2; ++m)
    #pragma unroll
    for (int r = 0; r < 4; ++r)
      #pragma unroll
      for (int jj = 0; jj < 3; ++jj) {
        float v = p[m][r][jj];
        v += __shfl_xor(v, 1); v += __shfl_xor(v, 2);
        v += __shfl_xor(v, 4); v += __shfl_xor(v, 8);
        p[m][r][jj] = v;
      }
  if (l15 == 0) {
    #pragma unroll
    for (int m = 0; m < 2; ++m)
      #pragma unroll
      for (int r = 0; r < 4; ++r) {
        const int rl = 16 * m + hi * 4 + r;
        S.red[wv][rl][0] = p[m][r][0];
        S.red[wv][rl][1] = p[m][r][1];
        S.red[wv][rl][2] = p[m][r][2];
      }
  }
  __syncthreads();

  if (t < 192) {
    const int row = t / 3, jj = t - (t / 3) * 3;
    const int wg = (row >> 5) * 4, rl = row & 31;
    float v = b3[jj] + S.red[wg][rl][jj] + S.red[wg + 1][rl][jj]
                     + S.red[wg + 2][rl][jj] + S.red[wg + 3][rl][jj];
    if (ST == 0) S.ext[row][jj] = v;
    else if (r0 + row < NROWS) out_pc[(size_t)(r0 + row) * 3 + jj] = v;
  }
  __syncthreads();
}

__global__ __launch_bounds__(512, 2) void fold5_kernel(
    const float* __restrict__ grid2, const float* __restrict__ h1b,
    const unsigned short* __restrict__ w2C,
    const float* __restrict__ f1w1, const float* __restrict__ f1b2,
    const float* __restrict__ f1w3, const float* __restrict__ f1b3,
    const float* __restrict__ f2w1, const float* __restrict__ f2b2,
    const float* __restrict__ f2w3, const float* __restrict__ f2b3,
    float* __restrict__ out_pc)
{
  __shared__ Fold5Smem S;
  const int t = threadIdx.x;
  const int r0 = blockIdx.x * 64;

  if (t < 64) {
    const int r = r0 + t;
    const int bb = min(r / MQ, NBATCH - 1);
    S.rowbb[t] = bb;
    const int m = min(r - bb * MQ, MQ - 1);
    S.ext[t][0] = grid2[m * 2 + 0];
    S.ext[t][1] = grid2[m * 2 + 1];
    S.ext[t][2] = 0.f;
    S.ext[t][3] = 0.f;
  }

  fold5_stage<0>(S, t, r0, h1b, f1w1, w2C,          f1b2, f1w3, f1b3, nullptr);
  fold5_stage<1>(S, t, r0, h1b, f2w1, w2C + 262144, f2b2, f2w3, f2b3, out_pc);
}

// =====================================================================
// cham: fused chamfer A + B + finalize (device-scope completion counter).
// blocks [0,512): A-side (min over m per input point)
// blocks [512,1024): B-side (min over n per output point)
// =====================================================================
__global__ __launch_bounds__(256) void cham_kernel(
    const float* __restrict__ pts, const float* __restrict__ pc,
    float* __restrict__ lacc, float* __restrict__ loss)
{
  __shared__ float s0[2048], s1[2048], s2[2048];
  const int t = threadIdx.x;
  const int side = blockIdx.x >> 9;
  const int ib = blockIdx.x & 511;
  const int b = ib >> 5;

  if (side == 0) {
    const int n0 = (ib & 31) << 6;
    const float* pcb = pc + (size_t)b * (MQ * 3);
    for (int i = t; i < MQ * 3; i += 256) {
      float v = pcb[i];
      int m = i / 3, j = i - m * 3;
      if (j == 0) s0[m] = v; else if (j == 1) s1[m] = v; else s2[m] = v;
    }
    for (int i = MQ + t; i < 2048; i += 256) { s0[i] = 1e30f; s1[i] = 1e30f; s2[i] = 1e30f; }
    __syncthreads();

    const int pid = t >> 4, q = t & 15;
    float ax[4], ay[4], az[4], mn[4];
    #pragma unroll
    for (int j = 0; j < 4; ++j) {
      const int n = n0 + pid * 4 + j;
      float4 P = *(const float4*)(pts + ((size_t)b * NPTS + n) * 4);
      ax[j] = P.x; ay[j] = P.y; az[j] = P.z + P.w; mn[j] = 1e30f;
    }
    #pragma unroll 4
    for (int i = 0; i < 32; ++i) {
      const int m4 = q * 4 + i * 64;
      float4 bx = *(const float4*)&s0[m4];
      float4 by = *(const float4*)&s1[m4];
      float4 bz = *(const float4*)&s2[m4];
      #pragma unroll
      for (int j = 0; j < 4; ++j) {
        float d0, dx, dy, dz;
        dx = ax[j] - bx.x; dy = ay[j] - by.x; dz = az[j] - bz.x; d0 = dx*dx + dy*dy + dz*dz; mn[j] = fminf(mn[j], d0);
        dx = ax[j] - bx.y; dy = ay[j] - by.y; dz = az[j] - bz.y; d0 = dx*dx + dy*dy + dz*dz; mn[j] = fminf(mn[j], d0);
        dx = ax[j] - bx.z; dy = ay[j] - by.z; dz = az[j] - bz.z; d0 = dx*dx + dy*dy + dz*dz; mn[j] = fminf(mn[j], d0);
        dx = ax[j] - bx.w; dy = ay[j] - by.w; dz = az[j] - bz.w; d0 = dx*dx + dy*dy + dz*dz; mn[j] = fminf(mn[j], d0);
      }
    }
    #pragma unroll
    for (int j = 0; j < 4; ++j) {
      mn[j] = fminf(mn[j], __shfl_xor(mn[j], 1));
      mn[j] = fminf(mn[j], __shfl_xor(mn[j], 2));
      mn[j] = fminf(mn[j], __shfl_xor(mn[j], 4));
      mn[j] = fminf(mn[j], __shfl_xor(mn[j], 8));
    }
    float v = (q == 0) ? (mn[0] + mn[1] + mn[2] + mn[3]) : 0.f;
    v += __shfl_xor(v, 16); v += __shfl_xor(v, 32);
    if ((t & 63) == 0) atomicAdd(lacc, v);
  } else {
    const int m0 = (ib & 31) << 6;
    for (int i = t; i < NPTS; i += 256) {
      float4 pp = *(const float4*)(pts + ((size_t)b * NPTS + i) * 4);
      s0[i] = pp.x; s1[i] = pp.y; s2[i] = pp.z + pp.w;
    }
    __syncthreads();

    const int pid = t >> 4, q = t & 15;
    float bx[4], by[4], bz[4], mn[4];
    bool vld[4];
    #pragma unroll
    for (int j = 0; j < 4; ++j) {
      const int m = m0 + pid * 4 + j;
      vld[j] = (m < MQ);
      const int mc = vld[j] ? m : (MQ - 1);
      bx[j] = pc[(size_t)b * (MQ * 3) + mc * 3 + 0];
      by[j] = pc[(size_t)b * (MQ * 3) + mc * 3 + 1];
      bz[j] = pc[(size_t)b * (MQ * 3) + mc * 3 + 2];
      mn[j] = 1e30f;
    }
    #pragma unroll 4
    for (int i = 0; i < 32; ++i) {
      const int n4 = q * 4 + i * 64;
      float4 axv = *(const float4*)&s0[n4];
      float4 ayv = *(const float4*)&s1[n4];
      float4 azv = *(const float4*)&s2[n4];
      #pragma unroll
      for (int j = 0; j < 4; ++j) {
        float d0, dx, dy, dz;
        dx = axv.x - bx[j]; dy = ayv.x - by[j]; dz = azv.x - bz[j]; d0 = dx*dx + dy*dy + dz*dz; mn[j] = fminf(mn[j], d0);
        dx = axv.y - bx[j]; dy = ayv.y - by[j]; dz = azv.y - bz[j]; d0 = dx*dx + dy*dy + dz*dz; mn[j] = fminf(mn[j], d0);
        dx = axv.z - bx[j]; dy = ayv.z - by[j]; dz = azv.z - bz[j]; d0 = dx*dx + dy*dy + dz*dz; mn[j] = fminf(mn[j], d0);
        dx = axv.w - bx[j]; dy = ayv.w - by[j]; dz = azv.w - bz[j]; d0 = dx*dx + dy*dy + dz*dz; mn[j] = fminf(mn[j], d0);
      }
    }
    #pragma unroll
    for (int j = 0; j < 4; ++j) {
      mn[j] = fminf(mn[j], __shfl_xor(mn[j], 1));
      mn[j] = fminf(mn[j], __shfl_xor(mn[j], 2));
      mn[j] = fminf(mn[j], __shfl_xor(mn[j], 4));
      mn[j] = fminf(mn[j], __shfl_xor(mn[j], 8));
    }
    float v = 0.f;
    if (q == 0) {
      #pragma unroll
      for (int j = 0; j < 4; ++j) if (vld[j]) v += mn[j];
    }
    v += __shfl_xor(v, 16); v += __shfl_xor(v, 32);
    if ((t & 63) == 0) atomicAdd(lacc + 1, v);
  }

  // ---- completion counter -> last block finalizes loss
  __syncthreads();
  if (t == 0) {
    __threadfence();
    unsigned old = atomicAdd((unsigned*)(lacc + 2), 1u);
    if (old == 1023u) {
      float l0 = atomicAdd(lacc, 0.f);       // coherent reads at L2
      float l1 = atomicAdd(lacc + 1, 0.f);
      loss[0] = l0 * (1.0f / (NBATCH * NPTS)) + l1 * (1.0f / (NBATCH * MQ));
    }
  }
}

// =====================================================================
extern "C" void kernel_launch(void* const* d_in, const int* in_sizes, int n_in,
                              void* d_out, int out_size, void* d_ws, size_t ws_size,
                              hipStream_t stream) {
  const float* pts  = (const float*)d_in[0];
  const float* ew1  = (const float*)d_in[1];
  const float* eb1  = (const float*)d_in[2];
  const float* ew2  = (const float*)d_in[3];
  const float* eb2  = (const float*)d_in[4];
  const float* ew3  = (const float*)d_in[5];
  const float* eb3  = (const float*)d_in[6];
  const float* f1w1 = (const float*)d_in[7];
  const float* f1b1 = (const float*)d_in[8];
  const float* f1w2 = (const float*)d_in[9];
  const float* f1b2 = (const float*)d_in[10];
  const float* f1w3 = (const float*)d_in[11];
  const float* f1b3 = (const float*)d_in[12];
  const float* f2w1 = (const float*)d_in[13];
  const float* f2b1 = (const float*)d_in[14];
  const float* f2w2 = (const float*)d_in[15];
  const float* f2b2 = (const float*)d_in[16];
  const float* f2w3 = (const float*)d_in[17];
  const float* f2b3 = (const float*)d_in[18];
  const float* grid2= (const float*)d_in[19];

  float* out = (float*)d_out;
  unsigned* keys       = (unsigned*)d_ws;                              // 32768 B
  float* lacc          = (float*)((char*)d_ws + 32768);                // 256 B (lacc0,lacc1,cnt)
  float* h1b           = (float*)((char*)d_ws + 33024);                // 65536 B -> 98560
  unsigned short* w2C  = (unsigned short*)((char*)d_ws + 98560);       // 1 MB -> 1147136
  unsigned short* ew2T = (unsigned short*)((char*)d_ws + 1147136);     // 16 KB
  unsigned short* ew3C = (unsigned short*)((char*)d_ws + 1163520);     // 128 KB

  prep_kernel<<<320, 256, 0, stream>>>(ew2, ew3, f1w2, f2w2,
                                       ew2T, ew3C, w2C, (unsigned*)d_ws);
  enc2_kernel<<<512, 512, 0, stream>>>(pts, ew1, eb1, ew2T, eb2, ew3C, eb3, keys);
  h1base_kernel<<<128, 256, 0, stream>>>(keys, out, f1w1, f1b1, f2w1, f2b1, h1b);
  fold5_kernel<<<507, 512, 0, stream>>>(grid2, h1b, w2C,
                                        f1w1, f1b2, f1w3, f1b3,
                                        f2w1, f2b2, f2w3, f2b3,
                                        out + 8192);                   // pc_out
  cham_kernel<<<1024, 256, 0, stream>>>(pts, out + 8192, lacc,
                                        out + 8192 + 97200);           // loss
}